// Round 6
// baseline (388.263 us; speedup 1.0000x reference)
//
#include <hip/hip_runtime.h>
#include <math.h>

#define E_TOT   10240
#define N_NODES 512
#define NCOL    11520

typedef unsigned short ushort_t;
typedef unsigned int   uint_t;
typedef __bf16 bf16x8 __attribute__((ext_vector_type(8)));
typedef float  f32x4  __attribute__((ext_vector_type(4)));

constexpr float EPSF        = 1e-5f;
constexpr float INV_SQRT128 = 0.08838834764831845f;
constexpr float INV_SQRT112 = 0.09449111825230681f;
constexpr float INV_SQRT48  = 0.14433756729740643f;
constexpr float INV_SQRT32  = 0.17677669529663687f;
constexpr float INV_SQRT16  = 0.25f;
constexpr float INV_SQRT8   = 0.35355339059327373f;
constexpr float SC0 = INV_SQRT128 * INV_SQRT112;
constexpr float SC1 = INV_SQRT128 * INV_SQRT48;
constexpr float SC2 = INV_SQRT128 * INV_SQRT16;
constexpr float C_OLD_ = 0.8944271909999159f;
constexpr float C_NEW_ = 0.4472135954999579f;
constexpr float NORMC  = 0.22360679774997896f;

// ---------------------------------------------------------------- utilities
__device__ __forceinline__ ushort_t f2bf(float x) {
  uint_t u = __float_as_uint(x);
  u = (u + 0x7fffu + ((u >> 16) & 1u)) >> 16;
  return (ushort_t)u;
}

// Analytic Wigner-D (l=2) in basis {xy, yz, 3z^2-1, xz, x^2-y^2}.
__device__ __forceinline__ void wigner5(const float q[9], float D[25]) {
  const float q0x=q[0],q0y=q[1],q0z=q[2];
  const float q1x=q[3],q1y=q[4],q1z=q[5];
  const float q2x=q[6],q2y=q[7],q2z=q[8];
  D[0]  = q0x*q1y + q1x*q0y;
  D[1]  = q0y*q1z + q1y*q0z;
  D[2]  = 0.5f*(q0z*q1z);
  D[3]  = q0x*q1z + q1x*q0z;
  D[4]  = 0.5f*(q0x*q1x - q0y*q1y);
  D[5]  = q1x*q2y + q2x*q1y;
  D[6]  = q1y*q2z + q2y*q1z;
  D[7]  = 0.5f*(q1z*q2z);
  D[8]  = q1x*q2z + q2x*q1z;
  D[9]  = 0.5f*(q1x*q2x - q1y*q2y);
  D[10] = 6.f*q2x*q2y;
  D[11] = 6.f*q2y*q2z;
  D[12] = 0.5f*(3.f*q2z*q2z - 1.f);
  D[13] = 6.f*q2x*q2z;
  D[14] = 1.5f*(q2x*q2x - q2y*q2y);
  D[15] = q0x*q2y + q2x*q0y;
  D[16] = q0y*q2z + q2y*q0z;
  D[17] = 0.5f*(q0z*q2z);
  D[18] = q0x*q2z + q2x*q0z;
  D[19] = 0.5f*(q0x*q2x - q0y*q2y);
  D[20] = 2.f*(q0x*q0y - q1x*q1y);
  D[21] = 2.f*(q0y*q0z - q1y*q1z);
  D[22] = 0.5f*(q0z*q0z - q1z*q1z);
  D[23] = 2.f*(q0x*q0z - q1x*q1z);
  D[24] = 0.5f*((q0x*q0x - q1x*q1x) - (q0y*q0y - q1y*q1y));
}

// ---------------------------- kA: W_tp pack + lat pack + zero + WenvT (fused)
// blocks [0,720): pack one tile of W_tp into contiguous-c MFMA fragments.
// blocks [720,5840): j = bid-720: latpack 256 elems, zero 288 oa_g elems,
//                    j<240: zero accg, j in [4000,4028): WenvT transpose.
__global__ void kA(const float* __restrict__ Wtp, const float* __restrict__ lat,
                   const float* __restrict__ Wenv,
                   ushort_t* __restrict__ Wp,
                   ushort_t* __restrict__ lath, ushort_t* __restrict__ latl,
                   float* __restrict__ oa_g, float* __restrict__ accg,
                   float* __restrict__ WenvT) {
  const int bid = blockIdx.x;
  const int t = threadIdx.x;
  if (bid < 720) {
    const int nt = bid;
    const int kc = t >> 6, lane = t & 63;
    const int m = lane & 15, kg = lane >> 4;
    int col, tt;
    if (nt < 560)      { col = nt/112; tt = nt - col*112; }
    else if (nt < 608) { col = 5;  tt = nt-560; }
    else if (nt < 632) { col = 6;  tt = nt-608; }
    else if (nt < 680) { col = 7;  tt = nt-632; }
    else if (nt < 704) { col = 8;  tt = nt-680; }
    else if (nt < 712) { col = 9;  tt = nt-704; }
    else               { col = 10; tt = nt-712; }
    int c; float sc;
    switch (col) {
      case 5:  c = 8960  + tt*24 + m;                       sc = SC1; break;
      case 6:  c = 8960  + (2*tt + (m>>3))*24 + 16 + (m&7); sc = SC1; break;
      case 7:  c = 10112 + tt*24 + m;                       sc = SC1; break;
      case 8:  c = 10112 + (2*tt + (m>>3))*24 + 16 + (m&7); sc = SC1; break;
      case 9:  c = 11264 + (2*tt + (m>>3))*8 + (m&7);       sc = SC2; break;
      case 10: c = 11392 + (2*tt + (m>>3))*8 + (m&7);       sc = SC2; break;
      default: c = tt*80 + col*16 + m;                      sc = SC0; break;
    }
    ushort_t hi[8], lo[8];
#pragma unroll
    for (int jj = 0; jj < 8; ++jj) {
      int l = kc*32 + kg*8 + jj;
      float w = Wtp[(size_t)l*NCOL + c] * sc;
      ushort_t h = f2bf(w);
      float hf = __uint_as_float(((uint_t)h) << 16);
      hi[jj] = h;
      lo[jj] = f2bf(w - hf);
    }
    size_t base = ((size_t)nt*8 + kc*2)*512 + (size_t)lane*8;
    *(uint4*)&Wp[base]       = *(const uint4*)hi;
    *(uint4*)&Wp[base + 512] = *(const uint4*)lo;
    return;
  }
  const int j = bid - 720;                 // 0..5119
  const int idx = j*256 + t;               // < 1,310,720 exactly
  {
    float x = lat[idx];
    ushort_t h = f2bf(x);
    float hf = __uint_as_float(((uint_t)h) << 16);
    lath[idx] = h;
    latl[idx] = f2bf(x - hf);
  }
#pragma unroll
  for (int i = t; i < 288; i += 256) oa_g[(size_t)j*288 + i] = 0.f;  // 5120*288 = 1,474,560
  if (j < 240) accg[j*256 + t] = 0.f;                                // 61,440
  if (j >= 4000 && j < 4028) {
    int q = (j-4000)*256 + t;              // < 7168
    int o = q >> 7, l = q & 127;
    WenvT[o*128 + l] = Wenv[l*56 + o];
  }
}

// ------------------------------------------------- K2: sln + per-edge preprocessing
// invT layout: [r][E_TOT] (r=0..239), writes coalesced across 32 edges.
// rows: in0 @0 (112) | inn1 @112 (48) | inp1 @160 (48) | inn2 @208 (16) | inp2 @224 (16)
__global__ __launch_bounds__(256)
void k2_edge_prep(const float* __restrict__ ndf,
                  const float* __restrict__ hid,
                  const float* __restrict__ evec,
                  const int*   __restrict__ eidx,
                  const int*   __restrict__ act,
                  const float* __restrict__ w0, const float* __restrict__ b0,
                  const float* __restrict__ w1, const float* __restrict__ w2,
                  float* __restrict__ invT,
                  float* __restrict__ Rm,
                  float* __restrict__ D2bm) {
  __shared__ float xs[32][240];      // [e][0:120 raw node feat | 120:240 hid]
  __shared__ float Rs[32][9];
  __shared__ float Dfs[32][25];
  __shared__ float muS[32], isS[32], invS[32];
  __shared__ int   ctrs[32];
  const int t = threadIdx.x;
  const int e0 = blockIdx.x*32;
  if (t < 32) {
    const int e = e0 + t;
    const int ae = act[e];
    ctrs[t] = eidx[ae];
    float vx = evec[ae*3+0], vy = evec[ae*3+1], vz = evec[ae*3+2];
    float rn = rsqrtf(vx*vx + vy*vy + vz*vz);
    float nx = vx*rn, ny = vy*rn, nz = vz*rn;
    float e1x, e1y, e1z;
    if (fabsf(nz) < 0.99f) { e1x = -ny; e1y = nx;  e1z = 0.f; }
    else                   { e1x = 0.f; e1y = -nz; e1z = ny;  }
    float rl = rsqrtf(e1x*e1x + e1y*e1y + e1z*e1z);
    e1x *= rl; e1y *= rl; e1z *= rl;
    float e2x = ny*e1z - nz*e1y;
    float e2y = nz*e1x - nx*e1z;
    float e2z = nx*e1y - ny*e1x;
    float R[9] = {e1x,e1y,e1z, e2x,e2y,e2z, nx,ny,nz};
#pragma unroll
    for (int jj = 0; jj < 9; ++jj) { Rs[t][jj] = R[jj]; Rm[(size_t)e*9 + jj] = R[jj]; }
    float Df[25];
    wigner5(R, Df);
#pragma unroll
    for (int jj = 0; jj < 25; ++jj) Dfs[t][jj] = Df[jj];
    float Rt[9] = {R[0],R[3],R[6], R[1],R[4],R[7], R[2],R[5],R[8]};
    float Db[25];
    wigner5(Rt, Db);
#pragma unroll
    for (int jj = 0; jj < 25; ++jj) D2bm[(size_t)e*25 + jj] = Db[jj];
  }
  __syncthreads();
  for (int i = t; i < 32*120; i += 256) {
    int s = i/120, jj = i - s*120;
    xs[s][jj]     = ndf[(size_t)ctrs[s]*120 + jj];
    xs[s][120+jj] = hid[(size_t)(e0+s)*120 + jj];
  }
  __syncthreads();
  if (t < 32) {
    float sum = 0.f, sq = 0.f;
#pragma unroll
    for (int i = 0; i < 32; ++i) { float v = xs[t][i]; sum += v; sq += v*v; }
    float mu = sum*(1.f/32.f);
    float var = sq*(1.f/32.f) - mu*mu;
    float v1s = 0.f, v2s = 0.f;
#pragma unroll
    for (int i = 32; i < 80; ++i) { float v = xs[t][i]; v1s += v*v; }
#pragma unroll
    for (int i = 80; i < 120; ++i) { float v = xs[t][i]; v2s += v*v; }
    muS[t] = mu;
    isS[t] = rsqrtf(var + EPSF);
    invS[t] = rsqrtf(0.5f*(v1s*(1.f/48.f) + v2s*(1.f/40.f)) + EPSF);
  }
  __syncthreads();
  const int e = t & 31, rb = t >> 5;
  const float* X  = xs[e];
  const float* Rr = Rs[e];
  const float* Df = Dfs[e];
  const float mu = muS[e], istd = isS[e], inv = invS[e];
#pragma unroll
  for (int r = rb; r < 240; r += 8) {
    float val;
    if (r < 64) {
      if (r < 32) val = (X[r] - mu)*istd*w0[r] + b0[r];
      else        val = X[88 + r];
    } else if (r < 96) {
      int u = r - 64; int b; float fac;
      if (u < 16) { b = 32 + 3*u; fac = inv*w1[u]; } else { b = 152 + 3*(u-16); fac = 1.f; }
      val = (Rr[3]*X[b] + Rr[4]*X[b+1] + Rr[5]*X[b+2])*fac;
    } else if (r < 112) {
      int u = r - 96; int b; float fac;
      if (u < 8) { b = 80 + 5*u; fac = inv*w2[u]; } else { b = 200 + 5*(u-8); fac = 1.f; }
      val = (Df[10]*X[b] + Df[11]*X[b+1] + Df[12]*X[b+2] + Df[13]*X[b+3] + Df[14]*X[b+4])*fac;
    } else if (r < 160) {
      int u = r - 112;
      if (u < 32) {
        int b; float fac;
        if (u < 16) { b = 32 + 3*u; fac = inv*w1[u]; } else { b = 152 + 3*(u-16); fac = 1.f; }
        val = (Rr[0]*X[b] + Rr[1]*X[b+1] + Rr[2]*X[b+2])*fac;
      } else {
        int u2 = u - 32; int b; float fac;
        if (u2 < 8) { b = 80 + 5*u2; fac = inv*w2[u2]; } else { b = 200 + 5*(u2-8); fac = 1.f; }
        val = (Df[5]*X[b] + Df[6]*X[b+1] + Df[7]*X[b+2] + Df[8]*X[b+3] + Df[9]*X[b+4])*fac;
      }
    } else if (r < 208) {
      int u = r - 160;
      if (u < 32) {
        int b; float fac;
        if (u < 16) { b = 32 + 3*u; fac = inv*w1[u]; } else { b = 152 + 3*(u-16); fac = 1.f; }
        val = (Rr[6]*X[b] + Rr[7]*X[b+1] + Rr[8]*X[b+2])*fac;
      } else {
        int u2 = u - 32; int b; float fac;
        if (u2 < 8) { b = 80 + 5*u2; fac = inv*w2[u2]; } else { b = 200 + 5*(u2-8); fac = 1.f; }
        val = (Df[15]*X[b] + Df[16]*X[b+1] + Df[17]*X[b+2] + Df[18]*X[b+3] + Df[19]*X[b+4])*fac;
      }
    } else if (r < 224) {
      int u = r - 208; int b; float fac;
      if (u < 8) { b = 80 + 5*u; fac = inv*w2[u]; } else { b = 200 + 5*(u-8); fac = 1.f; }
      val = (Df[0]*X[b] + Df[1]*X[b+1] + Df[2]*X[b+2] + Df[3]*X[b+3] + Df[4]*X[b+4])*fac;
    } else {
      int u = r - 224; int b; float fac;
      if (u < 8) { b = 80 + 5*u; fac = inv*w2[u]; } else { b = 200 + 5*(u-8); fac = 1.f; }
      val = (Df[20]*X[b] + Df[21]*X[b+1] + Df[22]*X[b+2] + Df[23]*X[b+3] + Df[24]*X[b+4])*fac;
    }
    invT[(size_t)r*E_TOT + e0 + e] = val;
  }
}

// --------------------------- K3: MFMA GEMM; 512 thr = 8 waves x 32 edges, A in LDS
// grid (40, 36): 256 edges/block, 20 tiles per y-slice (10 chunks of 2 tiles).
__global__ __launch_bounds__(512, 2)
void k3_gemm(const ushort_t* __restrict__ Wp,
             const ushort_t* __restrict__ lath,
             const ushort_t* __restrict__ latl,
             const float*  __restrict__ invT,
             float* __restrict__ oa_g) {
  __shared__ __align__(16) ushort_t abuf[2][8192];   // 2 x (2 tiles x 8 frags x 512)
  const int t = threadIdx.x;
  const int wave = t >> 6, lane = t & 63;
  const int le = lane & 15, g = lane >> 4, gh = g >> 1;
  const int fbase = blockIdx.y * 20;
  const int e0w = blockIdx.x*256 + wave*32;
  // ---- B fragments (wave's 32 edges, full K)
  bf16x8 Bh[4][2], Bl[4][2];
#pragma unroll
  for (int kc = 0; kc < 4; ++kc)
#pragma unroll
    for (int n = 0; n < 2; ++n) {
      size_t off = (size_t)(e0w + n*16 + le)*128 + kc*32 + g*8;
      Bh[kc][n] = *(const bf16x8*)(lath + off);
      Bl[kc][n] = *(const bf16x8*)(latl + off);
    }
  // ---- segment state (wave-uniform)
  int col, tt;
  if (fbase < 560)      { col = fbase/112; tt = fbase - col*112; }
  else if (fbase < 608) { col = 5;  tt = fbase-560; }
  else if (fbase < 632) { col = 6;  tt = fbase-608; }
  else if (fbase < 680) { col = 7;  tt = fbase-632; }
  else if (fbase < 704) { col = 8;  tt = fbase-680; }
  else if (fbase < 712) { col = 9;  tt = fbase-704; }
  else                  { col = 10; tt = fbase-712; }
  int mP_, mN_, sP_, sN_, segLen; float sg_; bool PAIR_, TWO_;
  auto setParams = [&](int cf) {
    if (cf < 5)       { segLen=112; mP_=0;   mN_=0;   sP_=cf*16; sN_=0;   sg_=1.f;  PAIR_=false; TWO_=false; }
    else if (cf == 5) { segLen=48;  mP_=160; mN_=112; sP_=80;  sN_=104; sg_=1.f;  PAIR_=false; TWO_=true; }
    else if (cf == 6) { segLen=24;  mP_=160; mN_=112; sP_=96;  sN_=120; sg_=1.f;  PAIR_=true;  TWO_=true; }
    else if (cf == 7) { segLen=48;  mP_=112; mN_=160; sP_=80;  sN_=104; sg_=-1.f; PAIR_=false; TWO_=true; }
    else if (cf == 8) { segLen=24;  mP_=112; mN_=160; sP_=96;  sN_=120; sg_=-1.f; PAIR_=true;  TWO_=true; }
    else if (cf == 9) { segLen=8;   mP_=224; mN_=208; sP_=128; sN_=136; sg_=1.f;  PAIR_=true;  TWO_=true; }
    else              { segLen=8;   mP_=208; mN_=224; sP_=128; sN_=136; sg_=-1.f; PAIR_=true;  TWO_=true; }
  };
  setParams(col);
  f32x4 aP0={0,0,0,0}, aP1={0,0,0,0}, aN0={0,0,0,0}, aN1={0,0,0,0};
  auto flush = [&]() {
#pragma unroll
    for (int r = 0; r < 4; ++r) {
      int mm = g*4 + r;
      int sp = sP_ + (PAIR_ ? (mm & 7) : mm);
      atomicAdd(&oa_g[(size_t)(e0w + le)*144 + sp], sg_*aP0[r]);
      atomicAdd(&oa_g[(size_t)(e0w + 16 + le)*144 + sp], sg_*aP1[r]);
      if (TWO_) {
        int sn = sN_ + (PAIR_ ? (mm & 7) : mm);
        atomicAdd(&oa_g[(size_t)(e0w + le)*144 + sn], aN0[r]);
        atomicAdd(&oa_g[(size_t)(e0w + 16 + le)*144 + sn], aN1[r]);
      }
    }
    aP0 = (f32x4){0,0,0,0}; aP1 = (f32x4){0,0,0,0};
    aN0 = (f32x4){0,0,0,0}; aN1 = (f32x4){0,0,0,0};
  };
  // ---- stage chunk 0: 16 rows of 512 ushorts; thread stages rows wave*2, wave*2+1
#pragma unroll
  for (int rr = 0; rr < 2; ++rr) {
    int row = wave*2 + rr;
    uint4 v = *(const uint4*)(Wp + ((size_t)(fbase + (row>>3))*8 + (row&7))*512 + lane*8);
    *(uint4*)&abuf[0][row*512 + lane*8] = v;
  }
  __syncthreads();
  // ---- main loop: 10 chunks of 2 tiles
  for (int c = 0; c < 10; ++c) {
    const int cb = c & 1, nb = cb ^ 1;
    uint4 pre[2];
    const bool more = (c + 1) < 10;
    if (more) {
#pragma unroll
      for (int rr = 0; rr < 2; ++rr) {
        int row = wave*2 + rr;
        pre[rr] = *(const uint4*)(Wp + ((size_t)(fbase + 2*(c+1) + (row>>3))*8 + (row&7))*512 + lane*8);
      }
    }
#pragma unroll
    for (int lt = 0; lt < 2; ++lt) {
      int idx = PAIR_ ? (2*tt + gh) : tt;
      int rowP = mP_ + idx;
      float mP0 = invT[(size_t)rowP*E_TOT + e0w + le];
      float mP1 = invT[(size_t)rowP*E_TOT + e0w + 16 + le];
      float mN0 = 0.f, mN1 = 0.f;
      if (TWO_) {
        int rowN = mN_ + idx;
        mN0 = invT[(size_t)rowN*E_TOT + e0w + le];
        mN1 = invT[(size_t)rowN*E_TOT + e0w + 16 + le];
      }
      f32x4 d0 = {0,0,0,0}, d1 = {0,0,0,0};
#pragma unroll
      for (int kc = 0; kc < 4; ++kc) {
        bf16x8 Ah = *(const bf16x8*)&abuf[cb][(lt*8 + kc*2 + 0)*512 + lane*8];
        bf16x8 Al = *(const bf16x8*)&abuf[cb][(lt*8 + kc*2 + 1)*512 + lane*8];
        d0 = __builtin_amdgcn_mfma_f32_16x16x32_bf16(Ah, Bh[kc][0], d0, 0, 0, 0);
        d1 = __builtin_amdgcn_mfma_f32_16x16x32_bf16(Ah, Bh[kc][1], d1, 0, 0, 0);
        d0 = __builtin_amdgcn_mfma_f32_16x16x32_bf16(Ah, Bl[kc][0], d0, 0, 0, 0);
        d1 = __builtin_amdgcn_mfma_f32_16x16x32_bf16(Ah, Bl[kc][1], d1, 0, 0, 0);
        d0 = __builtin_amdgcn_mfma_f32_16x16x32_bf16(Al, Bh[kc][0], d0, 0, 0, 0);
        d1 = __builtin_amdgcn_mfma_f32_16x16x32_bf16(Al, Bh[kc][1], d1, 0, 0, 0);
      }
#pragma unroll
      for (int r = 0; r < 4; ++r) { aP0[r] += mP0*d0[r]; aP1[r] += mP1*d1[r]; }
      if (TWO_) {
#pragma unroll
        for (int r = 0; r < 4; ++r) { aN0[r] += mN0*d0[r]; aN1[r] += mN1*d1[r]; }
      }
      tt++;
      if (tt == segLen) { flush(); col++; tt = 0; setParams(col); }
    }
    if (more) {
#pragma unroll
      for (int rr = 0; rr < 2; ++rr) {
        int row = wave*2 + rr;
        *(uint4*)&abuf[nb][row*512 + lane*8] = pre[rr];
      }
    }
    __syncthreads();
  }
  if (tt > 0) flush();
}

// -------------------------------------------- K4: per-edge epilogue + fused wenv
__global__ __launch_bounds__(256)
void k4_epi(const float* __restrict__ oa_g, const float* __restrict__ Rm,
            const float* __restrict__ D2bm,
            const float* __restrict__ lat, const float* __restrict__ WenvT,
            const int* __restrict__ eidx, const int* __restrict__ act,
            const float* __restrict__ Wp0, const float* __restrict__ bp0,
            const float* __restrict__ Wp1, const float* __restrict__ Wp2,
            float* __restrict__ accg) {
  __shared__ float sc[4][200];  // gates 0..55 | y1g 56..103 | y2g 104..143 | we 144..199
  const int wave = threadIdx.x >> 6, lane = threadIdx.x & 63;
  const int eg = blockIdx.x*4 + wave;
  const int ae = act[eg];
  const float* o_ = oa_g + (size_t)eg*144;
  if (lane < 56) {
    const float4* wv = (const float4*)(WenvT + lane*128);
    const float4* lv = (const float4*)(lat + (size_t)ae*128);
    float4 s4 = {0,0,0,0};
#pragma unroll
    for (int l4 = 0; l4 < 32; ++l4) {
      float4 a = lv[l4], b = wv[l4];
      s4.x += a.x*b.x; s4.y += a.y*b.y; s4.z += a.z*b.z; s4.w += a.w*b.w;
    }
    sc[wave][144 + lane] = (s4.x + s4.y + s4.z + s4.w) * INV_SQRT128;
    float v = o_[lane];
    sc[wave][lane] = (lane < 32) ? v/(1.f + expf(-v)) : 1.f/(1.f + expf(-v));
  }
  __syncthreads();
  const float* Rr = Rm + (size_t)eg*9;
  const float* Db = D2bm + (size_t)eg*25;
  if (lane < 48) {
    int u = lane/3, cc = lane - u*3;
    float yx = o_[104+u], yy = o_[56+u], yz = o_[80+u];
    float p = Rr[cc]*yx + Rr[3+cc]*yy + Rr[6+cc]*yz;
    sc[wave][56+lane] = p * sc[wave][32+u];
  }
  __syncthreads();
  if (lane < 40) {
    int u = lane/5, ii = lane - u*5;
    float y0 = o_[136+u], y1v = o_[120+u], y2v = o_[72+u], y3 = o_[96+u], y4 = o_[128+u];
    float p = Db[ii*5+0]*y0 + Db[ii*5+1]*y1v + Db[ii*5+2]*y2v + Db[ii*5+3]*y3 + Db[ii*5+4]*y4;
    sc[wave][104+lane] = p * sc[wave][48+u];
  }
  __syncthreads();
  const int ctr = eidx[ae];
  float* dst = accg + (size_t)ctr*120;
  const float* we = &sc[wave][144];
#pragma unroll
  for (int rnd = 0; rnd < 2; ++rnd) {
    int jo = rnd*64 + lane;
    if (jo < 120) {
      float val;
      if (jo < 32) {
        float s = 0.f;
#pragma unroll
        for (int i2 = 0; i2 < 32; ++i2) s += sc[wave][i2]*Wp0[i2*32 + jo];
        val = (s*INV_SQRT32 + bp0[jo]) * we[jo];
      } else if (jo < 80) {
        int jj = jo-32, v = jj/3, cc = jj - v*3;
        float s = 0.f;
#pragma unroll
        for (int u = 0; u < 16; ++u) s += sc[wave][56 + u*3 + cc]*Wp1[u*16 + v];
        val = s*INV_SQRT16*we[32+v];
      } else {
        int jj = jo-80, v = jj/5, ii = jj - v*5;
        float s = 0.f;
#pragma unroll
        for (int u = 0; u < 8; ++u) s += sc[wave][104 + u*5 + ii]*Wp2[u*8 + v];
        val = s*INV_SQRT8*we[48+v];
      }
      atomicAdd(&dst[jo], val);
    }
  }
}

// -------------------------------------------- K5: residual path + combine
__global__ void k5_final(const float* __restrict__ x_all,
                         const float* __restrict__ Wr0, const float* __restrict__ br0,
                         const float* __restrict__ Wr1, const float* __restrict__ Wr2,
                         const float* __restrict__ accg,
                         float* __restrict__ out) {
  const int n = blockIdx.x;
  const int t = threadIdx.x;
  if (t >= 120) return;
  const float* x = x_all + n*120;
  float r;
  if (t < 32) {
    float s = 0.f;
#pragma unroll
    for (int i = 0; i < 32; ++i) s += x[i]*Wr0[i*32 + t];
    r = s*INV_SQRT32 + br0[t];
  } else if (t < 80) {
    int j = t - 32, v = j/3, cp = j - 3*v;
    float s = 0.f;
#pragma unroll
    for (int u = 0; u < 16; ++u) s += x[32 + u*3 + cp]*Wr1[u*16 + v];
    r = s*INV_SQRT16;
  } else {
    int j = t - 80, v = j/5, cp = j - 5*v;
    float s = 0.f;
#pragma unroll
    for (int u = 0; u < 8; ++u) s += x[80 + u*5 + cp]*Wr2[u*8 + v];
    r = s*INV_SQRT8;
  }
  out[n*120 + t] = C_NEW_*(NORMC*accg[n*120 + t]) + C_OLD_*r;
}

// ---------------------------------------------------------------- launcher
extern "C" void kernel_launch(void* const* d_in, const int* in_sizes, int n_in,
                              void* d_out, int out_size, void* d_ws, size_t ws_size,
                              hipStream_t stream) {
  const float* lat  = (const float*)d_in[0];
  const float* ndf  = (const float*)d_in[1];
  const float* hid  = (const float*)d_in[2];
  const float* evec = (const float*)d_in[4];
  const float* Wtp  = (const float*)d_in[5];
  const float* Wenv = (const float*)d_in[6];
  const float* w0   = (const float*)d_in[7];
  const float* b0   = (const float*)d_in[8];
  const float* w1   = (const float*)d_in[9];
  const float* w2   = (const float*)d_in[10];
  const float* Wp0  = (const float*)d_in[11];
  const float* bp0  = (const float*)d_in[12];
  const float* Wp1  = (const float*)d_in[13];
  const float* Wp2  = (const float*)d_in[14];
  const float* Wr0  = (const float*)d_in[15];
  const float* br0  = (const float*)d_in[16];
  const float* Wr1  = (const float*)d_in[17];
  const float* Wr2  = (const float*)d_in[18];
  const int*   eidx = (const int*)d_in[20];
  const int*   act  = (const int*)d_in[21];
  float* out = (float*)d_out;

  char* p = (char*)d_ws;
  float*    invT  = (float*)(p + 245760);              // 9,830,400
  float*    Rm    = (float*)(p + 10076160);            // 368,640
  float*    D2bm  = (float*)(p + 10444800);            // 1,024,000
  float*    accg  = (float*)(p + 13762560);            // 245,760
  float*    oa_g  = (float*)(p + 14008320);            // 5,898,240
  ushort_t* lath  = (ushort_t*)(p + 19906560);         // 2,621,440
  ushort_t* latl  = (ushort_t*)(p + 22528000);         // 2,621,440
  ushort_t* Wpack = (ushort_t*)(p + 25149440);         // 5,898,240
  float*    WenvT = (float*)(p + 31047680);            // 28,672 (end 31,076,352)

  kA<<<5840, 256, 0, stream>>>(Wtp, lat, Wenv, Wpack, lath, latl, oa_g, accg, WenvT);
  k2_edge_prep<<<E_TOT/32, 256, 0, stream>>>(ndf, hid, evec, eidx, act,
                                             w0, b0, w1, w2, invT, Rm, D2bm);
  k3_gemm<<<dim3(E_TOT/256, 36), 512, 0, stream>>>(Wpack, lath, latl, invT, oa_g);
  k4_epi<<<E_TOT/4, 256, 0, stream>>>(oa_g, Rm, D2bm, lat, WenvT, eidx, act,
                                      Wp0, bp0, Wp1, Wp2, accg);
  k5_final<<<N_NODES, 128, 0, stream>>>(ndf, Wr0, br0, Wr1, Wr2, accg, out);
}

// Round 7
// 324.588 us; speedup vs baseline: 1.1962x; 1.1962x over previous
//
#include <hip/hip_runtime.h>
#include <math.h>

#define E_TOT   10240
#define N_NODES 512
#define NCOL    11520

typedef unsigned short ushort_t;
typedef unsigned int   uint_t;
typedef __bf16 bf16x8 __attribute__((ext_vector_type(8)));
typedef float  f32x4  __attribute__((ext_vector_type(4)));

constexpr float EPSF        = 1e-5f;
constexpr float INV_SQRT128 = 0.08838834764831845f;
constexpr float INV_SQRT112 = 0.09449111825230681f;
constexpr float INV_SQRT48  = 0.14433756729740643f;
constexpr float INV_SQRT32  = 0.17677669529663687f;
constexpr float INV_SQRT16  = 0.25f;
constexpr float INV_SQRT8   = 0.35355339059327373f;
constexpr float SC0 = INV_SQRT128 * INV_SQRT112;
constexpr float SC1 = INV_SQRT128 * INV_SQRT48;
constexpr float SC2 = INV_SQRT128 * INV_SQRT16;
constexpr float C_OLD_ = 0.8944271909999159f;
constexpr float C_NEW_ = 0.4472135954999579f;
constexpr float NORMC  = 0.22360679774997896f;

// ---------------------------------------------------------------- utilities
__device__ __forceinline__ ushort_t f2bf(float x) {
  uint_t u = __float_as_uint(x);
  u = (u + 0x7fffu + ((u >> 16) & 1u)) >> 16;
  return (ushort_t)u;
}

// Analytic Wigner-D (l=2) in basis {xy, yz, 3z^2-1, xz, x^2-y^2}.
__device__ __forceinline__ void wigner5(const float q[9], float D[25]) {
  const float q0x=q[0],q0y=q[1],q0z=q[2];
  const float q1x=q[3],q1y=q[4],q1z=q[5];
  const float q2x=q[6],q2y=q[7],q2z=q[8];
  D[0]  = q0x*q1y + q1x*q0y;
  D[1]  = q0y*q1z + q1y*q0z;
  D[2]  = 0.5f*(q0z*q1z);
  D[3]  = q0x*q1z + q1x*q0z;
  D[4]  = 0.5f*(q0x*q1x - q0y*q1y);
  D[5]  = q1x*q2y + q2x*q1y;
  D[6]  = q1y*q2z + q2y*q1z;
  D[7]  = 0.5f*(q1z*q2z);
  D[8]  = q1x*q2z + q2x*q1z;
  D[9]  = 0.5f*(q1x*q2x - q1y*q2y);
  D[10] = 6.f*q2x*q2y;
  D[11] = 6.f*q2y*q2z;
  D[12] = 0.5f*(3.f*q2z*q2z - 1.f);
  D[13] = 6.f*q2x*q2z;
  D[14] = 1.5f*(q2x*q2x - q2y*q2y);
  D[15] = q0x*q2y + q2x*q0y;
  D[16] = q0y*q2z + q2y*q0z;
  D[17] = 0.5f*(q0z*q2z);
  D[18] = q0x*q2z + q2x*q0z;
  D[19] = 0.5f*(q0x*q2x - q0y*q2y);
  D[20] = 2.f*(q0x*q0y - q1x*q1y);
  D[21] = 2.f*(q0y*q0z - q1y*q1z);
  D[22] = 0.5f*(q0z*q0z - q1z*q1z);
  D[23] = 2.f*(q0x*q0z - q1x*q1z);
  D[24] = 0.5f*((q0x*q0x - q1x*q1x) - (q0y*q0y - q1y*q1y));
}

// ---------------------------- kA: W_tp pack (coalesced via LDS) + lat pack + zero + WenvT
// blocks [0,720): pack one tile. Phase1: coalesced 128(l)x16(c) load into LDS.
// blocks [720,5840): j = bid-720: latpack 256 elems, zero 288 oa_g elems,
//                    j<240: zero accg, j in [4000,4028): WenvT transpose.
__global__ void kA(const float* __restrict__ Wtp, const float* __restrict__ lat,
                   const float* __restrict__ Wenv,
                   ushort_t* __restrict__ Wp,
                   ushort_t* __restrict__ lath, ushort_t* __restrict__ latl,
                   float* __restrict__ oa_g, float* __restrict__ accg,
                   float* __restrict__ WenvT) {
  __shared__ float Wl[128*17];     // [l][m], pad 17
  const int bid = blockIdx.x;
  const int t = threadIdx.x;
  if (bid < 720) {
    const int nt = bid;
    int col, tt;
    if (nt < 560)      { col = nt/112; tt = nt - col*112; }
    else if (nt < 608) { col = 5;  tt = nt-560; }
    else if (nt < 632) { col = 6;  tt = nt-608; }
    else if (nt < 680) { col = 7;  tt = nt-632; }
    else if (nt < 704) { col = 8;  tt = nt-680; }
    else if (nt < 712) { col = 9;  tt = nt-704; }
    else               { col = 10; tt = nt-712; }
    float sc;
    // phase 1: lane m1 = t&15 loads column c(m1) for rows l = p*16 + (t>>4)
    {
      const int m1 = t & 15, lp = t >> 4;
      int c;
      switch (col) {
        case 5:  c = 8960  + tt*24 + m1;                        sc = SC1; break;
        case 6:  c = 8960  + (2*tt + (m1>>3))*24 + 16 + (m1&7); sc = SC1; break;
        case 7:  c = 10112 + tt*24 + m1;                        sc = SC1; break;
        case 8:  c = 10112 + (2*tt + (m1>>3))*24 + 16 + (m1&7); sc = SC1; break;
        case 9:  c = 11264 + (2*tt + (m1>>3))*8 + (m1&7);       sc = SC2; break;
        case 10: c = 11392 + (2*tt + (m1>>3))*8 + (m1&7);       sc = SC2; break;
        default: c = tt*80 + col*16 + m1;                       sc = SC0; break;
      }
#pragma unroll
      for (int p = 0; p < 8; ++p) {
        int l = p*16 + lp;
        Wl[l*17 + m1] = Wtp[(size_t)l*NCOL + c] * sc;
      }
    }
    __syncthreads();
    // phase 2: compose fragments from LDS
    const int kc = t >> 6, lane = t & 63;
    const int m = lane & 15, kg = lane >> 4;
    ushort_t hi[8], lo[8];
#pragma unroll
    for (int jj = 0; jj < 8; ++jj) {
      int l = kc*32 + kg*8 + jj;
      float w = Wl[l*17 + m];
      ushort_t h = f2bf(w);
      float hf = __uint_as_float(((uint_t)h) << 16);
      hi[jj] = h;
      lo[jj] = f2bf(w - hf);
    }
    size_t base = ((size_t)nt*8 + kc*2)*512 + (size_t)lane*8;
    *(uint4*)&Wp[base]       = *(const uint4*)hi;
    *(uint4*)&Wp[base + 512] = *(const uint4*)lo;
    return;
  }
  const int j = bid - 720;                 // 0..5119
  const int idx = j*256 + t;               // < 1,310,720 exactly
  {
    float x = lat[idx];
    ushort_t h = f2bf(x);
    float hf = __uint_as_float(((uint_t)h) << 16);
    lath[idx] = h;
    latl[idx] = f2bf(x - hf);
  }
#pragma unroll
  for (int i = t; i < 288; i += 256) oa_g[(size_t)j*288 + i] = 0.f;  // 5120*288 = 1,474,560
  if (j < 240) accg[j*256 + t] = 0.f;                                // 61,440
  if (j >= 4000 && j < 4028) {
    int q = (j-4000)*256 + t;              // < 7168
    int o = q >> 7, l = q & 127;
    WenvT[o*128 + l] = Wenv[l*56 + o];
  }
}

// ------------------------------------------------- K2: sln + per-edge preprocessing
// invT layout: [r][E_TOT] (r=0..239), writes coalesced across 32 edges.
// rows: in0 @0 (112) | inn1 @112 (48) | inp1 @160 (48) | inn2 @208 (16) | inp2 @224 (16)
__global__ __launch_bounds__(256)
void k2_edge_prep(const float* __restrict__ ndf,
                  const float* __restrict__ hid,
                  const float* __restrict__ evec,
                  const int*   __restrict__ eidx,
                  const int*   __restrict__ act,
                  const float* __restrict__ w0, const float* __restrict__ b0,
                  const float* __restrict__ w1, const float* __restrict__ w2,
                  float* __restrict__ invT,
                  float* __restrict__ Rm,
                  float* __restrict__ D2bm) {
  __shared__ float xs[32][240];      // [e][0:120 raw node feat | 120:240 hid]
  __shared__ float Rs[32][9];
  __shared__ float Dfs[32][25];
  __shared__ float muS[32], isS[32], invS[32];
  __shared__ int   ctrs[32];
  const int t = threadIdx.x;
  const int e0 = blockIdx.x*32;
  if (t < 32) {
    const int e = e0 + t;
    const int ae = act[e];
    ctrs[t] = eidx[ae];
    float vx = evec[ae*3+0], vy = evec[ae*3+1], vz = evec[ae*3+2];
    float rn = rsqrtf(vx*vx + vy*vy + vz*vz);
    float nx = vx*rn, ny = vy*rn, nz = vz*rn;
    float e1x, e1y, e1z;
    if (fabsf(nz) < 0.99f) { e1x = -ny; e1y = nx;  e1z = 0.f; }
    else                   { e1x = 0.f; e1y = -nz; e1z = ny;  }
    float rl = rsqrtf(e1x*e1x + e1y*e1y + e1z*e1z);
    e1x *= rl; e1y *= rl; e1z *= rl;
    float e2x = ny*e1z - nz*e1y;
    float e2y = nz*e1x - nx*e1z;
    float e2z = nx*e1y - ny*e1x;
    float R[9] = {e1x,e1y,e1z, e2x,e2y,e2z, nx,ny,nz};
#pragma unroll
    for (int jj = 0; jj < 9; ++jj) { Rs[t][jj] = R[jj]; Rm[(size_t)e*9 + jj] = R[jj]; }
    float Df[25];
    wigner5(R, Df);
#pragma unroll
    for (int jj = 0; jj < 25; ++jj) Dfs[t][jj] = Df[jj];
    float Rt[9] = {R[0],R[3],R[6], R[1],R[4],R[7], R[2],R[5],R[8]};
    float Db[25];
    wigner5(Rt, Db);
#pragma unroll
    for (int jj = 0; jj < 25; ++jj) D2bm[(size_t)e*25 + jj] = Db[jj];
  }
  __syncthreads();
  for (int i = t; i < 32*120; i += 256) {
    int s = i/120, jj = i - s*120;
    xs[s][jj]     = ndf[(size_t)ctrs[s]*120 + jj];
    xs[s][120+jj] = hid[(size_t)(e0+s)*120 + jj];
  }
  __syncthreads();
  if (t < 32) {
    float sum = 0.f, sq = 0.f;
#pragma unroll
    for (int i = 0; i < 32; ++i) { float v = xs[t][i]; sum += v; sq += v*v; }
    float mu = sum*(1.f/32.f);
    float var = sq*(1.f/32.f) - mu*mu;
    float v1s = 0.f, v2s = 0.f;
#pragma unroll
    for (int i = 32; i < 80; ++i) { float v = xs[t][i]; v1s += v*v; }
#pragma unroll
    for (int i = 80; i < 120; ++i) { float v = xs[t][i]; v2s += v*v; }
    muS[t] = mu;
    isS[t] = rsqrtf(var + EPSF);
    invS[t] = rsqrtf(0.5f*(v1s*(1.f/48.f) + v2s*(1.f/40.f)) + EPSF);
  }
  __syncthreads();
  const int e = t & 31, rb = t >> 5;
  const float* X  = xs[e];
  const float* Rr = Rs[e];
  const float* Df = Dfs[e];
  const float mu = muS[e], istd = isS[e], inv = invS[e];
#pragma unroll
  for (int r = rb; r < 240; r += 8) {
    float val;
    if (r < 64) {
      if (r < 32) val = (X[r] - mu)*istd*w0[r] + b0[r];
      else        val = X[88 + r];
    } else if (r < 96) {
      int u = r - 64; int b; float fac;
      if (u < 16) { b = 32 + 3*u; fac = inv*w1[u]; } else { b = 152 + 3*(u-16); fac = 1.f; }
      val = (Rr[3]*X[b] + Rr[4]*X[b+1] + Rr[5]*X[b+2])*fac;
    } else if (r < 112) {
      int u = r - 96; int b; float fac;
      if (u < 8) { b = 80 + 5*u; fac = inv*w2[u]; } else { b = 200 + 5*(u-8); fac = 1.f; }
      val = (Df[10]*X[b] + Df[11]*X[b+1] + Df[12]*X[b+2] + Df[13]*X[b+3] + Df[14]*X[b+4])*fac;
    } else if (r < 160) {
      int u = r - 112;
      if (u < 32) {
        int b; float fac;
        if (u < 16) { b = 32 + 3*u; fac = inv*w1[u]; } else { b = 152 + 3*(u-16); fac = 1.f; }
        val = (Rr[0]*X[b] + Rr[1]*X[b+1] + Rr[2]*X[b+2])*fac;
      } else {
        int u2 = u - 32; int b; float fac;
        if (u2 < 8) { b = 80 + 5*u2; fac = inv*w2[u2]; } else { b = 200 + 5*(u2-8); fac = 1.f; }
        val = (Df[5]*X[b] + Df[6]*X[b+1] + Df[7]*X[b+2] + Df[8]*X[b+3] + Df[9]*X[b+4])*fac;
      }
    } else if (r < 208) {
      int u = r - 160;
      if (u < 32) {
        int b; float fac;
        if (u < 16) { b = 32 + 3*u; fac = inv*w1[u]; } else { b = 152 + 3*(u-16); fac = 1.f; }
        val = (Rr[6]*X[b] + Rr[7]*X[b+1] + Rr[8]*X[b+2])*fac;
      } else {
        int u2 = u - 32; int b; float fac;
        if (u2 < 8) { b = 80 + 5*u2; fac = inv*w2[u2]; } else { b = 200 + 5*(u2-8); fac = 1.f; }
        val = (Df[15]*X[b] + Df[16]*X[b+1] + Df[17]*X[b+2] + Df[18]*X[b+3] + Df[19]*X[b+4])*fac;
      }
    } else if (r < 224) {
      int u = r - 208; int b; float fac;
      if (u < 8) { b = 80 + 5*u; fac = inv*w2[u]; } else { b = 200 + 5*(u-8); fac = 1.f; }
      val = (Df[0]*X[b] + Df[1]*X[b+1] + Df[2]*X[b+2] + Df[3]*X[b+3] + Df[4]*X[b+4])*fac;
    } else {
      int u = r - 224; int b; float fac;
      if (u < 8) { b = 80 + 5*u; fac = inv*w2[u]; } else { b = 200 + 5*(u-8); fac = 1.f; }
      val = (Df[20]*X[b] + Df[21]*X[b+1] + Df[22]*X[b+2] + Df[23]*X[b+3] + Df[24]*X[b+4])*fac;
    }
    invT[(size_t)r*E_TOT + e0 + e] = val;
  }
}

// --------------------------- K3: MFMA GEMM; 4 waves x 32 edges, A in LDS (R4 structure)
// grid (80, 18): 128 edges/block, 40 tiles per y-slice (20 chunks of 2 tiles).
__global__ __launch_bounds__(256, 2)
void k3_gemm(const ushort_t* __restrict__ Wp,
             const ushort_t* __restrict__ lath,
             const ushort_t* __restrict__ latl,
             const float*  __restrict__ invT,
             float* __restrict__ oa_g) {
  __shared__ __align__(16) ushort_t abuf[2][8192];   // 2 x (2 tiles x 8 frags x 512)
  const int t = threadIdx.x;
  const int wave = t >> 6, lane = t & 63;
  const int le = lane & 15, g = lane >> 4, gh = g >> 1;
  const int fbase = blockIdx.y * 40;
  const int e0w = blockIdx.x*128 + wave*32;
  // ---- B fragments (wave's 32 edges)
  bf16x8 Bh[4][2], Bl[4][2];
#pragma unroll
  for (int kc = 0; kc < 4; ++kc)
#pragma unroll
    for (int n = 0; n < 2; ++n) {
      size_t off = (size_t)(e0w + n*16 + le)*128 + kc*32 + g*8;
      Bh[kc][n] = *(const bf16x8*)(lath + off);
      Bl[kc][n] = *(const bf16x8*)(latl + off);
    }
  // ---- segment state (wave-uniform scalars)
  int col, tt;
  if (fbase < 560)      { col = fbase/112; tt = fbase - col*112; }
  else if (fbase < 608) { col = 5;  tt = fbase-560; }
  else if (fbase < 632) { col = 6;  tt = fbase-608; }
  else if (fbase < 680) { col = 7;  tt = fbase-632; }
  else if (fbase < 704) { col = 8;  tt = fbase-680; }
  else if (fbase < 712) { col = 9;  tt = fbase-704; }
  else                  { col = 10; tt = fbase-712; }
  int mP_, mN_, sP_, sN_, segLen; float sg_; bool PAIR_, TWO_;
  auto setParams = [&](int cf) {
    if (cf < 5)       { segLen=112; mP_=0;   mN_=0;   sP_=cf*16; sN_=0;   sg_=1.f;  PAIR_=false; TWO_=false; }
    else if (cf == 5) { segLen=48;  mP_=160; mN_=112; sP_=80;  sN_=104; sg_=1.f;  PAIR_=false; TWO_=true; }
    else if (cf == 6) { segLen=24;  mP_=160; mN_=112; sP_=96;  sN_=120; sg_=1.f;  PAIR_=true;  TWO_=true; }
    else if (cf == 7) { segLen=48;  mP_=112; mN_=160; sP_=80;  sN_=104; sg_=-1.f; PAIR_=false; TWO_=true; }
    else if (cf == 8) { segLen=24;  mP_=112; mN_=160; sP_=96;  sN_=120; sg_=-1.f; PAIR_=true;  TWO_=true; }
    else if (cf == 9) { segLen=8;   mP_=224; mN_=208; sP_=128; sN_=136; sg_=1.f;  PAIR_=true;  TWO_=true; }
    else              { segLen=8;   mP_=208; mN_=224; sP_=128; sN_=136; sg_=-1.f; PAIR_=true;  TWO_=true; }
  };
  setParams(col);
  f32x4 aP0={0,0,0,0}, aP1={0,0,0,0}, aN0={0,0,0,0}, aN1={0,0,0,0};
  auto flush = [&]() {
#pragma unroll
    for (int r = 0; r < 4; ++r) {
      int mm = g*4 + r;
      int sp = sP_ + (PAIR_ ? (mm & 7) : mm);
      atomicAdd(&oa_g[(size_t)(e0w + le)*144 + sp], sg_*aP0[r]);
      atomicAdd(&oa_g[(size_t)(e0w + 16 + le)*144 + sp], sg_*aP1[r]);
      if (TWO_) {
        int sn = sN_ + (PAIR_ ? (mm & 7) : mm);
        atomicAdd(&oa_g[(size_t)(e0w + le)*144 + sn], aN0[r]);
        atomicAdd(&oa_g[(size_t)(e0w + 16 + le)*144 + sn], aN1[r]);
      }
    }
    aP0 = (f32x4){0,0,0,0}; aP1 = (f32x4){0,0,0,0};
    aN0 = (f32x4){0,0,0,0}; aN1 = (f32x4){0,0,0,0};
  };
  // ---- stage chunk 0
#pragma unroll
  for (int qq = 0; qq < 4; ++qq) {
    uint4 v = *(const uint4*)(Wp + ((size_t)fbase*8 + wave*4 + qq)*512 + lane*8);
    *(uint4*)&abuf[0][(wave*4 + qq)*512 + lane*8] = v;
  }
  __syncthreads();
  // ---- main loop: 20 chunks of 2 tiles
  for (int c = 0; c < 20; ++c) {
    const int cb = c & 1, nb = cb ^ 1;
    uint4 pre[4];
    const bool more = (c + 1) < 20;
    if (more) {
#pragma unroll
      for (int qq = 0; qq < 4; ++qq)
        pre[qq] = *(const uint4*)(Wp + ((size_t)(fbase + 2*(c+1))*8 + wave*4 + qq)*512 + lane*8);
    }
#pragma unroll
    for (int lt = 0; lt < 2; ++lt) {
      int idx = PAIR_ ? (2*tt + gh) : tt;
      int rowP = mP_ + idx;
      float mP0 = invT[(size_t)rowP*E_TOT + e0w + le];
      float mP1 = invT[(size_t)rowP*E_TOT + e0w + 16 + le];
      float mN0 = 0.f, mN1 = 0.f;
      if (TWO_) {
        int rowN = mN_ + idx;
        mN0 = invT[(size_t)rowN*E_TOT + e0w + le];
        mN1 = invT[(size_t)rowN*E_TOT + e0w + 16 + le];
      }
      f32x4 d0 = {0,0,0,0}, d1 = {0,0,0,0};
#pragma unroll
      for (int kc = 0; kc < 4; ++kc) {
        bf16x8 Ah = *(const bf16x8*)&abuf[cb][(lt*8 + kc*2 + 0)*512 + lane*8];
        bf16x8 Al = *(const bf16x8*)&abuf[cb][(lt*8 + kc*2 + 1)*512 + lane*8];
        d0 = __builtin_amdgcn_mfma_f32_16x16x32_bf16(Ah, Bh[kc][0], d0, 0, 0, 0);
        d1 = __builtin_amdgcn_mfma_f32_16x16x32_bf16(Ah, Bh[kc][1], d1, 0, 0, 0);
        d0 = __builtin_amdgcn_mfma_f32_16x16x32_bf16(Ah, Bl[kc][0], d0, 0, 0, 0);
        d1 = __builtin_amdgcn_mfma_f32_16x16x32_bf16(Ah, Bl[kc][1], d1, 0, 0, 0);
        d0 = __builtin_amdgcn_mfma_f32_16x16x32_bf16(Al, Bh[kc][0], d0, 0, 0, 0);
        d1 = __builtin_amdgcn_mfma_f32_16x16x32_bf16(Al, Bh[kc][1], d1, 0, 0, 0);
      }
#pragma unroll
      for (int r = 0; r < 4; ++r) { aP0[r] += mP0*d0[r]; aP1[r] += mP1*d1[r]; }
      if (TWO_) {
#pragma unroll
        for (int r = 0; r < 4; ++r) { aN0[r] += mN0*d0[r]; aN1[r] += mN1*d1[r]; }
      }
      tt++;
      if (tt == segLen) { flush(); col++; tt = 0; setParams(col); }
    }
    if (more) {
#pragma unroll
      for (int qq = 0; qq < 4; ++qq)
        *(uint4*)&abuf[nb][(wave*4 + qq)*512 + lane*8] = pre[qq];
    }
    __syncthreads();
  }
  if (tt > 0) flush();
}

// -------------------------------------------- K4: per-edge epilogue + fused wenv
__global__ __launch_bounds__(256)
void k4_epi(const float* __restrict__ oa_g, const float* __restrict__ Rm,
            const float* __restrict__ D2bm,
            const float* __restrict__ lat, const float* __restrict__ WenvT,
            const int* __restrict__ eidx, const int* __restrict__ act,
            const float* __restrict__ Wp0, const float* __restrict__ bp0,
            const float* __restrict__ Wp1, const float* __restrict__ Wp2,
            float* __restrict__ accg) {
  __shared__ float sc[4][200];  // gates 0..55 | y1g 56..103 | y2g 104..143 | we 144..199
  const int wave = threadIdx.x >> 6, lane = threadIdx.x & 63;
  const int eg = blockIdx.x*4 + wave;
  const int ae = act[eg];
  const float* o_ = oa_g + (size_t)eg*144;
  if (lane < 56) {
    const float4* wv = (const float4*)(WenvT + lane*128);
    const float4* lv = (const float4*)(lat + (size_t)ae*128);
    float4 s4 = {0,0,0,0};
#pragma unroll
    for (int l4 = 0; l4 < 32; ++l4) {
      float4 a = lv[l4], b = wv[l4];
      s4.x += a.x*b.x; s4.y += a.y*b.y; s4.z += a.z*b.z; s4.w += a.w*b.w;
    }
    sc[wave][144 + lane] = (s4.x + s4.y + s4.z + s4.w) * INV_SQRT128;
    float v = o_[lane];
    sc[wave][lane] = (lane < 32) ? v/(1.f + expf(-v)) : 1.f/(1.f + expf(-v));
  }
  __syncthreads();
  const float* Rr = Rm + (size_t)eg*9;
  const float* Db = D2bm + (size_t)eg*25;
  if (lane < 48) {
    int u = lane/3, cc = lane - u*3;
    float yx = o_[104+u], yy = o_[56+u], yz = o_[80+u];
    float p = Rr[cc]*yx + Rr[3+cc]*yy + Rr[6+cc]*yz;
    sc[wave][56+lane] = p * sc[wave][32+u];
  }
  __syncthreads();
  if (lane < 40) {
    int u = lane/5, ii = lane - u*5;
    float y0 = o_[136+u], y1v = o_[120+u], y2v = o_[72+u], y3 = o_[96+u], y4 = o_[128+u];
    float p = Db[ii*5+0]*y0 + Db[ii*5+1]*y1v + Db[ii*5+2]*y2v + Db[ii*5+3]*y3 + Db[ii*5+4]*y4;
    sc[wave][104+lane] = p * sc[wave][48+u];
  }
  __syncthreads();
  const int ctr = eidx[ae];
  float* dst = accg + (size_t)ctr*120;
  const float* we = &sc[wave][144];
#pragma unroll
  for (int rnd = 0; rnd < 2; ++rnd) {
    int jo = rnd*64 + lane;
    if (jo < 120) {
      float val;
      if (jo < 32) {
        float s = 0.f;
#pragma unroll
        for (int i2 = 0; i2 < 32; ++i2) s += sc[wave][i2]*Wp0[i2*32 + jo];
        val = (s*INV_SQRT32 + bp0[jo]) * we[jo];
      } else if (jo < 80) {
        int jj = jo-32, v = jj/3, cc = jj - v*3;
        float s = 0.f;
#pragma unroll
        for (int u = 0; u < 16; ++u) s += sc[wave][56 + u*3 + cc]*Wp1[u*16 + v];
        val = s*INV_SQRT16*we[32+v];
      } else {
        int jj = jo-80, v = jj/5, ii = jj - v*5;
        float s = 0.f;
#pragma unroll
        for (int u = 0; u < 8; ++u) s += sc[wave][104 + u*5 + ii]*Wp2[u*8 + v];
        val = s*INV_SQRT8*we[48+v];
      }
      atomicAdd(&dst[jo], val);
    }
  }
}

// -------------------------------------------- K5: residual path + combine
__global__ void k5_final(const float* __restrict__ x_all,
                         const float* __restrict__ Wr0, const float* __restrict__ br0,
                         const float* __restrict__ Wr1, const float* __restrict__ Wr2,
                         const float* __restrict__ accg,
                         float* __restrict__ out) {
  const int n = blockIdx.x;
  const int t = threadIdx.x;
  if (t >= 120) return;
  const float* x = x_all + n*120;
  float r;
  if (t < 32) {
    float s = 0.f;
#pragma unroll
    for (int i = 0; i < 32; ++i) s += x[i]*Wr0[i*32 + t];
    r = s*INV_SQRT32 + br0[t];
  } else if (t < 80) {
    int j = t - 32, v = j/3, cp = j - 3*v;
    float s = 0.f;
#pragma unroll
    for (int u = 0; u < 16; ++u) s += x[32 + u*3 + cp]*Wr1[u*16 + v];
    r = s*INV_SQRT16;
  } else {
    int j = t - 80, v = j/5, cp = j - 5*v;
    float s = 0.f;
#pragma unroll
    for (int u = 0; u < 8; ++u) s += x[80 + u*5 + cp]*Wr2[u*8 + v];
    r = s*INV_SQRT8;
  }
  out[n*120 + t] = C_NEW_*(NORMC*accg[n*120 + t]) + C_OLD_*r;
}

// ---------------------------------------------------------------- launcher
extern "C" void kernel_launch(void* const* d_in, const int* in_sizes, int n_in,
                              void* d_out, int out_size, void* d_ws, size_t ws_size,
                              hipStream_t stream) {
  const float* lat  = (const float*)d_in[0];
  const float* ndf  = (const float*)d_in[1];
  const float* hid  = (const float*)d_in[2];
  const float* evec = (const float*)d_in[4];
  const float* Wtp  = (const float*)d_in[5];
  const float* Wenv = (const float*)d_in[6];
  const float* w0   = (const float*)d_in[7];
  const float* b0   = (const float*)d_in[8];
  const float* w1   = (const float*)d_in[9];
  const float* w2   = (const float*)d_in[10];
  const float* Wp0  = (const float*)d_in[11];
  const float* bp0  = (const float*)d_in[12];
  const float* Wp1  = (const float*)d_in[13];
  const float* Wp2  = (const float*)d_in[14];
  const float* Wr0  = (const float*)d_in[15];
  const float* br0  = (const float*)d_in[16];
  const float* Wr1  = (const float*)d_in[17];
  const float* Wr2  = (const float*)d_in[18];
  const int*   eidx = (const int*)d_in[20];
  const int*   act  = (const int*)d_in[21];
  float* out = (float*)d_out;

  char* p = (char*)d_ws;
  float*    invT  = (float*)(p + 245760);              // 9,830,400
  float*    Rm    = (float*)(p + 10076160);            // 368,640
  float*    D2bm  = (float*)(p + 10444800);            // 1,024,000
  float*    accg  = (float*)(p + 13762560);            // 245,760
  float*    oa_g  = (float*)(p + 14008320);            // 5,898,240
  ushort_t* lath  = (ushort_t*)(p + 19906560);         // 2,621,440
  ushort_t* latl  = (ushort_t*)(p + 22528000);         // 2,621,440
  ushort_t* Wpack = (ushort_t*)(p + 25149440);         // 5,898,240
  float*    WenvT = (float*)(p + 31047680);            // 28,672 (end 31,076,352)

  kA<<<5840, 256, 0, stream>>>(Wtp, lat, Wenv, Wpack, lath, latl, oa_g, accg, WenvT);
  k2_edge_prep<<<E_TOT/32, 256, 0, stream>>>(ndf, hid, evec, eidx, act,
                                             w0, b0, w1, w2, invT, Rm, D2bm);
  k3_gemm<<<dim3(E_TOT/128, 18), 256, 0, stream>>>(Wpack, lath, latl, invT, oa_g);
  k4_epi<<<E_TOT/4, 256, 0, stream>>>(oa_g, Rm, D2bm, lat, WenvT, eidx, act,
                                      Wp0, bp0, Wp1, Wp2, accg);
  k5_final<<<N_NODES, 128, 0, stream>>>(ndf, Wr0, br0, Wr1, Wr2, accg, out);
}

// Round 8
// 303.344 us; speedup vs baseline: 1.2799x; 1.0700x over previous
//
#include <hip/hip_runtime.h>
#include <math.h>

#define E_TOT   10240
#define N_NODES 512
#define NCOL    11520

typedef unsigned short ushort_t;
typedef unsigned int   uint_t;
typedef __bf16 bf16x8 __attribute__((ext_vector_type(8)));
typedef float  f32x4  __attribute__((ext_vector_type(4)));

constexpr float EPSF        = 1e-5f;
constexpr float INV_SQRT128 = 0.08838834764831845f;
constexpr float INV_SQRT112 = 0.09449111825230681f;
constexpr float INV_SQRT48  = 0.14433756729740643f;
constexpr float INV_SQRT32  = 0.17677669529663687f;
constexpr float INV_SQRT16  = 0.25f;
constexpr float INV_SQRT8   = 0.35355339059327373f;
constexpr float SC0 = INV_SQRT128 * INV_SQRT112;
constexpr float SC1 = INV_SQRT128 * INV_SQRT48;
constexpr float SC2 = INV_SQRT128 * INV_SQRT16;
constexpr float C_OLD_ = 0.8944271909999159f;
constexpr float C_NEW_ = 0.4472135954999579f;
constexpr float NORMC  = 0.22360679774997896f;
constexpr float OUTSC  = C_NEW_ * NORMC;        // scale on message path into out

// ---------------------------------------------------------------- utilities
__device__ __forceinline__ ushort_t f2bf(float x) {
  uint_t u = __float_as_uint(x);
  u = (u + 0x7fffu + ((u >> 16) & 1u)) >> 16;
  return (ushort_t)u;
}

// Analytic Wigner-D (l=2) in basis {xy, yz, 3z^2-1, xz, x^2-y^2}.
__device__ __forceinline__ void wigner5(const float q[9], float D[25]) {
  const float q0x=q[0],q0y=q[1],q0z=q[2];
  const float q1x=q[3],q1y=q[4],q1z=q[5];
  const float q2x=q[6],q2y=q[7],q2z=q[8];
  D[0]  = q0x*q1y + q1x*q0y;
  D[1]  = q0y*q1z + q1y*q0z;
  D[2]  = 0.5f*(q0z*q1z);
  D[3]  = q0x*q1z + q1x*q0z;
  D[4]  = 0.5f*(q0x*q1x - q0y*q1y);
  D[5]  = q1x*q2y + q2x*q1y;
  D[6]  = q1y*q2z + q2y*q1z;
  D[7]  = 0.5f*(q1z*q2z);
  D[8]  = q1x*q2z + q2x*q1z;
  D[9]  = 0.5f*(q1x*q2x - q1y*q2y);
  D[10] = 6.f*q2x*q2y;
  D[11] = 6.f*q2y*q2z;
  D[12] = 0.5f*(3.f*q2z*q2z - 1.f);
  D[13] = 6.f*q2x*q2z;
  D[14] = 1.5f*(q2x*q2x - q2y*q2y);
  D[15] = q0x*q2y + q2x*q0y;
  D[16] = q0y*q2z + q2y*q0z;
  D[17] = 0.5f*(q0z*q2z);
  D[18] = q0x*q2z + q2x*q0z;
  D[19] = 0.5f*(q0x*q2x - q0y*q2y);
  D[20] = 2.f*(q0x*q0y - q1x*q1y);
  D[21] = 2.f*(q0y*q0z - q1y*q1z);
  D[22] = 0.5f*(q0z*q0z - q1z*q1z);
  D[23] = 2.f*(q0x*q0z - q1x*q1z);
  D[24] = 0.5f*((q0x*q0x - q1x*q1x) - (q0y*q0y - q1y*q1y));
}

// ============================ kAB: all independent prep work in ONE dispatch
// bid [0,720)        : pack W_tp tile -> contiguous-c MFMA bf16 hi/lo fragments
// bid [720,5840)     : j=bid-720: latpack 256 elems; zero 288 oa_g; WenvT transpose
// bid [5840,6160)    : edge-prep (sln + frames + Wigner + so2 inputs) for 32 edges
// bid [6160,6672)    : residual init: out[n] = C_OLD * ir_linear(ndf)[n]
__global__ __launch_bounds__(256)
void kAB(const float* __restrict__ Wtp, const float* __restrict__ lat,
         const float* __restrict__ Wenv,
         const float* __restrict__ ndf, const float* __restrict__ hid,
         const float* __restrict__ evec,
         const int* __restrict__ eidx, const int* __restrict__ act,
         const float* __restrict__ w0, const float* __restrict__ b0,
         const float* __restrict__ w1, const float* __restrict__ w2,
         const float* __restrict__ Wr0, const float* __restrict__ br0,
         const float* __restrict__ Wr1, const float* __restrict__ Wr2,
         ushort_t* __restrict__ Wp,
         ushort_t* __restrict__ lath, ushort_t* __restrict__ latl,
         float* __restrict__ oa_g, float* __restrict__ WenvT,
         float* __restrict__ invT, float* __restrict__ Rm,
         float* __restrict__ D2bm, float* __restrict__ out) {
  __shared__ __align__(16) char smem[35584];
  const int bid = blockIdx.x;
  const int t = threadIdx.x;
  if (bid < 720) {
    // ---------------- W_tp pack (coalesced via LDS transpose)
    float* Wl = (float*)smem;           // [l][m] pad 17
    const int nt = bid;
    int col, tt;
    if (nt < 560)      { col = nt/112; tt = nt - col*112; }
    else if (nt < 608) { col = 5;  tt = nt-560; }
    else if (nt < 632) { col = 6;  tt = nt-608; }
    else if (nt < 680) { col = 7;  tt = nt-632; }
    else if (nt < 704) { col = 8;  tt = nt-680; }
    else if (nt < 712) { col = 9;  tt = nt-704; }
    else               { col = 10; tt = nt-712; }
    {
      const int m1 = t & 15, lp = t >> 4;
      int c; float sc;
      switch (col) {
        case 5:  c = 8960  + tt*24 + m1;                        sc = SC1; break;
        case 6:  c = 8960  + (2*tt + (m1>>3))*24 + 16 + (m1&7); sc = SC1; break;
        case 7:  c = 10112 + tt*24 + m1;                        sc = SC1; break;
        case 8:  c = 10112 + (2*tt + (m1>>3))*24 + 16 + (m1&7); sc = SC1; break;
        case 9:  c = 11264 + (2*tt + (m1>>3))*8 + (m1&7);       sc = SC2; break;
        case 10: c = 11392 + (2*tt + (m1>>3))*8 + (m1&7);       sc = SC2; break;
        default: c = tt*80 + col*16 + m1;                       sc = SC0; break;
      }
#pragma unroll
      for (int p = 0; p < 8; ++p) {
        int l = p*16 + lp;
        Wl[l*17 + m1] = Wtp[(size_t)l*NCOL + c] * sc;
      }
    }
    __syncthreads();
    const int kc = t >> 6, lane = t & 63;
    const int m = lane & 15, kg = lane >> 4;
    ushort_t hi[8], lo[8];
#pragma unroll
    for (int jj = 0; jj < 8; ++jj) {
      int l = kc*32 + kg*8 + jj;
      float w = Wl[l*17 + m];
      ushort_t h = f2bf(w);
      float hf = __uint_as_float(((uint_t)h) << 16);
      hi[jj] = h;
      lo[jj] = f2bf(w - hf);
    }
    size_t base = ((size_t)nt*8 + kc*2)*512 + (size_t)lane*8;
    *(uint4*)&Wp[base]       = *(const uint4*)hi;
    *(uint4*)&Wp[base + 512] = *(const uint4*)lo;
    return;
  }
  if (bid < 5840) {
    // ---------------- latpack + zero oa_g + WenvT
    const int j = bid - 720;                 // 0..5119
    const int idx = j*256 + t;
    float x = lat[idx];
    ushort_t h = f2bf(x);
    float hf = __uint_as_float(((uint_t)h) << 16);
    lath[idx] = h;
    latl[idx] = f2bf(x - hf);
#pragma unroll
    for (int i = t; i < 288; i += 256) oa_g[(size_t)j*288 + i] = 0.f;
    if (j >= 4000 && j < 4028) {
      int q = (j-4000)*256 + t;              // < 7168
      int o = q >> 7, l = q & 127;
      WenvT[o*128 + l] = Wenv[l*56 + o];
    }
    return;
  }
  if (bid < 6160) {
    // ---------------- edge prep (sln fused), 32 edges
    float (*xs)[240] = (float(*)[240])smem;                 // 30720
    float (*Rs)[9]   = (float(*)[9])(smem + 30720);         // 1152
    float (*Dfs)[25] = (float(*)[25])(smem + 31872);        // 3200
    float* muS  = (float*)(smem + 35072);
    float* isS  = (float*)(smem + 35200);
    float* invS = (float*)(smem + 35328);
    int*   ctrs = (int*)(smem + 35456);
    const int e0 = (bid - 5840)*32;
    if (t < 32) {
      const int e = e0 + t;
      const int ae = act[e];
      ctrs[t] = eidx[ae];
      float vx = evec[ae*3+0], vy = evec[ae*3+1], vz = evec[ae*3+2];
      float rn = rsqrtf(vx*vx + vy*vy + vz*vz);
      float nx = vx*rn, ny = vy*rn, nz = vz*rn;
      float e1x, e1y, e1z;
      if (fabsf(nz) < 0.99f) { e1x = -ny; e1y = nx;  e1z = 0.f; }
      else                   { e1x = 0.f; e1y = -nz; e1z = ny;  }
      float rl = rsqrtf(e1x*e1x + e1y*e1y + e1z*e1z);
      e1x *= rl; e1y *= rl; e1z *= rl;
      float e2x = ny*e1z - nz*e1y;
      float e2y = nz*e1x - nx*e1z;
      float e2z = nx*e1y - ny*e1x;
      float R[9] = {e1x,e1y,e1z, e2x,e2y,e2z, nx,ny,nz};
#pragma unroll
      for (int jj = 0; jj < 9; ++jj) { Rs[t][jj] = R[jj]; Rm[(size_t)e*9 + jj] = R[jj]; }
      float Df[25];
      wigner5(R, Df);
#pragma unroll
      for (int jj = 0; jj < 25; ++jj) Dfs[t][jj] = Df[jj];
      float Rt[9] = {R[0],R[3],R[6], R[1],R[4],R[7], R[2],R[5],R[8]};
      float Db[25];
      wigner5(Rt, Db);
#pragma unroll
      for (int jj = 0; jj < 25; ++jj) D2bm[(size_t)e*25 + jj] = Db[jj];
    }
    __syncthreads();
    for (int i = t; i < 32*120; i += 256) {
      int s = i/120, jj = i - s*120;
      xs[s][jj]     = ndf[(size_t)ctrs[s]*120 + jj];
      xs[s][120+jj] = hid[(size_t)(e0+s)*120 + jj];
    }
    __syncthreads();
    if (t < 32) {
      float sum = 0.f, sq = 0.f;
#pragma unroll
      for (int i = 0; i < 32; ++i) { float v = xs[t][i]; sum += v; sq += v*v; }
      float mu = sum*(1.f/32.f);
      float var = sq*(1.f/32.f) - mu*mu;
      float v1s = 0.f, v2s = 0.f;
#pragma unroll
      for (int i = 32; i < 80; ++i) { float v = xs[t][i]; v1s += v*v; }
#pragma unroll
      for (int i = 80; i < 120; ++i) { float v = xs[t][i]; v2s += v*v; }
      muS[t] = mu;
      isS[t] = rsqrtf(var + EPSF);
      invS[t] = rsqrtf(0.5f*(v1s*(1.f/48.f) + v2s*(1.f/40.f)) + EPSF);
    }
    __syncthreads();
    const int e = t & 31, rb = t >> 5;
    const float* X  = xs[e];
    const float* Rr = Rs[e];
    const float* Df = Dfs[e];
    const float mu = muS[e], istd = isS[e], inv = invS[e];
#pragma unroll
    for (int r = rb; r < 240; r += 8) {
      float val;
      if (r < 64) {
        if (r < 32) val = (X[r] - mu)*istd*w0[r] + b0[r];
        else        val = X[88 + r];
      } else if (r < 96) {
        int u = r - 64; int b; float fac;
        if (u < 16) { b = 32 + 3*u; fac = inv*w1[u]; } else { b = 152 + 3*(u-16); fac = 1.f; }
        val = (Rr[3]*X[b] + Rr[4]*X[b+1] + Rr[5]*X[b+2])*fac;
      } else if (r < 112) {
        int u = r - 96; int b; float fac;
        if (u < 8) { b = 80 + 5*u; fac = inv*w2[u]; } else { b = 200 + 5*(u-8); fac = 1.f; }
        val = (Df[10]*X[b] + Df[11]*X[b+1] + Df[12]*X[b+2] + Df[13]*X[b+3] + Df[14]*X[b+4])*fac;
      } else if (r < 160) {
        int u = r - 112;
        if (u < 32) {
          int b; float fac;
          if (u < 16) { b = 32 + 3*u; fac = inv*w1[u]; } else { b = 152 + 3*(u-16); fac = 1.f; }
          val = (Rr[0]*X[b] + Rr[1]*X[b+1] + Rr[2]*X[b+2])*fac;
        } else {
          int u2 = u - 32; int b; float fac;
          if (u2 < 8) { b = 80 + 5*u2; fac = inv*w2[u2]; } else { b = 200 + 5*(u2-8); fac = 1.f; }
          val = (Df[5]*X[b] + Df[6]*X[b+1] + Df[7]*X[b+2] + Df[8]*X[b+3] + Df[9]*X[b+4])*fac;
        }
      } else if (r < 208) {
        int u = r - 160;
        if (u < 32) {
          int b; float fac;
          if (u < 16) { b = 32 + 3*u; fac = inv*w1[u]; } else { b = 152 + 3*(u-16); fac = 1.f; }
          val = (Rr[6]*X[b] + Rr[7]*X[b+1] + Rr[8]*X[b+2])*fac;
        } else {
          int u2 = u - 32; int b; float fac;
          if (u2 < 8) { b = 80 + 5*u2; fac = inv*w2[u2]; } else { b = 200 + 5*(u2-8); fac = 1.f; }
          val = (Df[15]*X[b] + Df[16]*X[b+1] + Df[17]*X[b+2] + Df[18]*X[b+3] + Df[19]*X[b+4])*fac;
        }
      } else if (r < 224) {
        int u = r - 208; int b; float fac;
        if (u < 8) { b = 80 + 5*u; fac = inv*w2[u]; } else { b = 200 + 5*(u-8); fac = 1.f; }
        val = (Df[0]*X[b] + Df[1]*X[b+1] + Df[2]*X[b+2] + Df[3]*X[b+3] + Df[4]*X[b+4])*fac;
      } else {
        int u = r - 224; int b; float fac;
        if (u < 8) { b = 80 + 5*u; fac = inv*w2[u]; } else { b = 200 + 5*(u-8); fac = 1.f; }
        val = (Df[20]*X[b] + Df[21]*X[b+1] + Df[22]*X[b+2] + Df[23]*X[b+3] + Df[24]*X[b+4])*fac;
      }
      invT[(size_t)r*E_TOT + e0 + e] = val;
    }
    return;
  }
  // ---------------- residual init: out = C_OLD * ir_linear(ndf)
  {
    const int n = bid - 6160;
    if (t >= 120) return;
    const float* x = ndf + (size_t)n*120;
    float r;
    if (t < 32) {
      float s = 0.f;
#pragma unroll
      for (int i = 0; i < 32; ++i) s += x[i]*Wr0[i*32 + t];
      r = s*INV_SQRT32 + br0[t];
    } else if (t < 80) {
      int j = t - 32, v = j/3, cp = j - 3*v;
      float s = 0.f;
#pragma unroll
      for (int u = 0; u < 16; ++u) s += x[32 + u*3 + cp]*Wr1[u*16 + v];
      r = s*INV_SQRT16;
    } else {
      int j = t - 80, v = j/5, cp = j - 5*v;
      float s = 0.f;
#pragma unroll
      for (int u = 0; u < 8; ++u) s += x[80 + u*5 + cp]*Wr2[u*8 + v];
      r = s*INV_SQRT8;
    }
    out[(size_t)n*120 + t] = C_OLD_*r;
  }
}

// ============================ K3: MFMA GEMM (R4 shape + split acc + hoisted gathers)
struct Seg { int col, tt, mP, mN, sP, sN, segLen; float sg; bool PAIR, TWO; };
__device__ __forceinline__ void setp(Seg& s) {
  const int cf = s.col;
  if (cf < 5)       { s.segLen=112; s.mP=0;   s.mN=0;   s.sP=cf*16; s.sN=0;   s.sg=1.f;  s.PAIR=false; s.TWO=false; }
  else if (cf == 5) { s.segLen=48;  s.mP=160; s.mN=112; s.sP=80;  s.sN=104; s.sg=1.f;  s.PAIR=false; s.TWO=true; }
  else if (cf == 6) { s.segLen=24;  s.mP=160; s.mN=112; s.sP=96;  s.sN=120; s.sg=1.f;  s.PAIR=true;  s.TWO=true; }
  else if (cf == 7) { s.segLen=48;  s.mP=112; s.mN=160; s.sP=80;  s.sN=104; s.sg=-1.f; s.PAIR=false; s.TWO=true; }
  else if (cf == 8) { s.segLen=24;  s.mP=112; s.mN=160; s.sP=96;  s.sN=120; s.sg=-1.f; s.PAIR=true;  s.TWO=true; }
  else if (cf == 9) { s.segLen=8;   s.mP=224; s.mN=208; s.sP=128; s.sN=136; s.sg=1.f;  s.PAIR=true;  s.TWO=true; }
  else              { s.segLen=8;   s.mP=208; s.mN=224; s.sP=128; s.sN=136; s.sg=-1.f; s.PAIR=true;  s.TWO=true; }
}
__device__ __forceinline__ bool adv(Seg& s) {   // returns true if crossed segment
  s.tt++;
  if (s.tt == s.segLen) { s.col++; s.tt = 0; setp(s); return true; }
  return false;
}

__global__ __launch_bounds__(256, 2)
void k3_gemm(const ushort_t* __restrict__ Wp,
             const ushort_t* __restrict__ lath,
             const ushort_t* __restrict__ latl,
             const float*  __restrict__ invT,
             float* __restrict__ oa_g) {
  __shared__ __align__(16) ushort_t abuf[2][8192];   // 2 x (2 tiles x 8 frags x 512)
  const int t = threadIdx.x;
  const int wave = t >> 6, lane = t & 63;
  const int le = lane & 15, g = lane >> 4, gh = g >> 1;
  const int fbase = blockIdx.y * 80;
  const int e0w = blockIdx.x*128 + wave*32;
  // ---- B fragments (wave's 32 edges)
  bf16x8 Bh[4][2], Bl[4][2];
#pragma unroll
  for (int kc = 0; kc < 4; ++kc)
#pragma unroll
    for (int n = 0; n < 2; ++n) {
      size_t off = (size_t)(e0w + n*16 + le)*128 + kc*32 + g*8;
      Bh[kc][n] = *(const bf16x8*)(lath + off);
      Bl[kc][n] = *(const bf16x8*)(latl + off);
    }
  // ---- segment state
  Seg s;
  if (fbase < 560)      { s.col = fbase/112; s.tt = fbase - s.col*112; }
  else if (fbase < 608) { s.col = 5;  s.tt = fbase-560; }
  else if (fbase < 632) { s.col = 6;  s.tt = fbase-608; }
  else if (fbase < 680) { s.col = 7;  s.tt = fbase-632; }
  else if (fbase < 704) { s.col = 8;  s.tt = fbase-680; }
  else if (fbase < 712) { s.col = 9;  s.tt = fbase-704; }
  else                  { s.col = 10; s.tt = fbase-712; }
  setp(s);
  f32x4 aP0={0,0,0,0}, aP1={0,0,0,0}, aN0={0,0,0,0}, aN1={0,0,0,0};
  auto flushSeg = [&](const Seg& fs) {
#pragma unroll
    for (int r = 0; r < 4; ++r) {
      int mm = g*4 + r;
      int sp = fs.sP + (fs.PAIR ? (mm & 7) : mm);
      atomicAdd(&oa_g[(size_t)(e0w + le)*144 + sp], fs.sg*aP0[r]);
      atomicAdd(&oa_g[(size_t)(e0w + 16 + le)*144 + sp], fs.sg*aP1[r]);
      if (fs.TWO) {
        int sn = fs.sN + (fs.PAIR ? (mm & 7) : mm);
        atomicAdd(&oa_g[(size_t)(e0w + le)*144 + sn], aN0[r]);
        atomicAdd(&oa_g[(size_t)(e0w + 16 + le)*144 + sn], aN1[r]);
      }
    }
    aP0 = (f32x4){0,0,0,0}; aP1 = (f32x4){0,0,0,0};
    aN0 = (f32x4){0,0,0,0}; aN1 = (f32x4){0,0,0,0};
  };
  // ---- stage chunk 0
#pragma unroll
  for (int qq = 0; qq < 4; ++qq) {
    uint4 v = *(const uint4*)(Wp + ((size_t)fbase*8 + wave*4 + qq)*512 + lane*8);
    *(uint4*)&abuf[0][(wave*4 + qq)*512 + lane*8] = v;
  }
  __syncthreads();
  // ---- main loop: 40 chunks of 2 tiles
  for (int c = 0; c < 40; ++c) {
    const int cb = c & 1, nb = cb ^ 1;
    uint4 pre[4];
    const bool more = (c + 1) < 40;
    if (more) {
#pragma unroll
      for (int qq = 0; qq < 4; ++qq)
        pre[qq] = *(const uint4*)(Wp + ((size_t)(fbase + 2*(c+1))*8 + wave*4 + qq)*512 + lane*8);
    }
    // segment states for both tiles of this chunk; issue ALL gathers up front
    Seg s1 = s;
    const bool cross0 = adv(s1);
    const int idx0 = s.PAIR  ? (2*s.tt  + gh) : s.tt;
    const int idx1 = s1.PAIR ? (2*s1.tt + gh) : s1.tt;
    float g0P0 = invT[(size_t)(s.mP + idx0)*E_TOT + e0w + le];
    float g0P1 = invT[(size_t)(s.mP + idx0)*E_TOT + e0w + 16 + le];
    float g1P0 = invT[(size_t)(s1.mP + idx1)*E_TOT + e0w + le];
    float g1P1 = invT[(size_t)(s1.mP + idx1)*E_TOT + e0w + 16 + le];
    float g0N0 = 0.f, g0N1 = 0.f, g1N0 = 0.f, g1N1 = 0.f;
    if (s.TWO) {
      g0N0 = invT[(size_t)(s.mN + idx0)*E_TOT + e0w + le];
      g0N1 = invT[(size_t)(s.mN + idx0)*E_TOT + e0w + 16 + le];
    }
    if (s1.TWO) {
      g1N0 = invT[(size_t)(s1.mN + idx1)*E_TOT + e0w + le];
      g1N1 = invT[(size_t)(s1.mN + idx1)*E_TOT + e0w + 16 + le];
    }
    // ---- tile 0 (lt = 0): split accumulators -> 4 independent 6-deep chains
    {
      f32x4 dE0={0,0,0,0}, dO0={0,0,0,0}, dE1={0,0,0,0}, dO1={0,0,0,0};
#pragma unroll
      for (int kc = 0; kc < 2; ++kc) {
        bf16x8 Ah = *(const bf16x8*)&abuf[cb][(kc*2 + 0)*512 + lane*8];
        bf16x8 Al = *(const bf16x8*)&abuf[cb][(kc*2 + 1)*512 + lane*8];
        dE0 = __builtin_amdgcn_mfma_f32_16x16x32_bf16(Ah, Bh[kc][0], dE0, 0, 0, 0);
        dE1 = __builtin_amdgcn_mfma_f32_16x16x32_bf16(Ah, Bh[kc][1], dE1, 0, 0, 0);
        dE0 = __builtin_amdgcn_mfma_f32_16x16x32_bf16(Ah, Bl[kc][0], dE0, 0, 0, 0);
        dE1 = __builtin_amdgcn_mfma_f32_16x16x32_bf16(Ah, Bl[kc][1], dE1, 0, 0, 0);
        dE0 = __builtin_amdgcn_mfma_f32_16x16x32_bf16(Al, Bh[kc][0], dE0, 0, 0, 0);
        dE1 = __builtin_amdgcn_mfma_f32_16x16x32_bf16(Al, Bh[kc][1], dE1, 0, 0, 0);
      }
#pragma unroll
      for (int kc = 2; kc < 4; ++kc) {
        bf16x8 Ah = *(const bf16x8*)&abuf[cb][(kc*2 + 0)*512 + lane*8];
        bf16x8 Al = *(const bf16x8*)&abuf[cb][(kc*2 + 1)*512 + lane*8];
        dO0 = __builtin_amdgcn_mfma_f32_16x16x32_bf16(Ah, Bh[kc][0], dO0, 0, 0, 0);
        dO1 = __builtin_amdgcn_mfma_f32_16x16x32_bf16(Ah, Bh[kc][1], dO1, 0, 0, 0);
        dO0 = __builtin_amdgcn_mfma_f32_16x16x32_bf16(Ah, Bl[kc][0], dO0, 0, 0, 0);
        dO1 = __builtin_amdgcn_mfma_f32_16x16x32_bf16(Ah, Bl[kc][1], dO1, 0, 0, 0);
        dO0 = __builtin_amdgcn_mfma_f32_16x16x32_bf16(Al, Bh[kc][0], dO0, 0, 0, 0);
        dO1 = __builtin_amdgcn_mfma_f32_16x16x32_bf16(Al, Bh[kc][1], dO1, 0, 0, 0);
      }
      f32x4 d0 = dE0 + dO0, d1 = dE1 + dO1;
#pragma unroll
      for (int r = 0; r < 4; ++r) { aP0[r] += g0P0*d0[r]; aP1[r] += g0P1*d1[r]; }
      if (s.TWO) {
#pragma unroll
        for (int r = 0; r < 4; ++r) { aN0[r] += g0N0*d0[r]; aN1[r] += g0N1*d1[r]; }
      }
    }
    if (cross0) flushSeg(s);
    // ---- tile 1 (lt = 1)
    {
      f32x4 dE0={0,0,0,0}, dO0={0,0,0,0}, dE1={0,0,0,0}, dO1={0,0,0,0};
#pragma unroll
      for (int kc = 0; kc < 2; ++kc) {
        bf16x8 Ah = *(const bf16x8*)&abuf[cb][(8 + kc*2 + 0)*512 + lane*8];
        bf16x8 Al = *(const bf16x8*)&abuf[cb][(8 + kc*2 + 1)*512 + lane*8];
        dE0 = __builtin_amdgcn_mfma_f32_16x16x32_bf16(Ah, Bh[kc][0], dE0, 0, 0, 0);
        dE1 = __builtin_amdgcn_mfma_f32_16x16x32_bf16(Ah, Bh[kc][1], dE1, 0, 0, 0);
        dE0 = __builtin_amdgcn_mfma_f32_16x16x32_bf16(Ah, Bl[kc][0], dE0, 0, 0, 0);
        dE1 = __builtin_amdgcn_mfma_f32_16x16x32_bf16(Ah, Bl[kc][1], dE1, 0, 0, 0);
        dE0 = __builtin_amdgcn_mfma_f32_16x16x32_bf16(Al, Bh[kc][0], dE0, 0, 0, 0);
        dE1 = __builtin_amdgcn_mfma_f32_16x16x32_bf16(Al, Bh[kc][1], dE1, 0, 0, 0);
      }
#pragma unroll
      for (int kc = 2; kc < 4; ++kc) {
        bf16x8 Ah = *(const bf16x8*)&abuf[cb][(8 + kc*2 + 0)*512 + lane*8];
        bf16x8 Al = *(const bf16x8*)&abuf[cb][(8 + kc*2 + 1)*512 + lane*8];
        dO0 = __builtin_amdgcn_mfma_f32_16x16x32_bf16(Ah, Bh[kc][0], dO0, 0, 0, 0);
        dO1 = __builtin_amdgcn_mfma_f32_16x16x32_bf16(Ah, Bh[kc][1], dO1, 0, 0, 0);
        dO0 = __builtin_amdgcn_mfma_f32_16x16x32_bf16(Ah, Bl[kc][0], dO0, 0, 0, 0);
        dO1 = __builtin_amdgcn_mfma_f32_16x16x32_bf16(Ah, Bl[kc][1], dO1, 0, 0, 0);
        dO0 = __builtin_amdgcn_mfma_f32_16x16x32_bf16(Al, Bh[kc][0], dO0, 0, 0, 0);
        dO1 = __builtin_amdgcn_mfma_f32_16x16x32_bf16(Al, Bh[kc][1], dO1, 0, 0, 0);
      }
      f32x4 d0 = dE0 + dO0, d1 = dE1 + dO1;
#pragma unroll
      for (int r = 0; r < 4; ++r) { aP0[r] += g1P0*d0[r]; aP1[r] += g1P1*d1[r]; }
      if (s1.TWO) {
#pragma unroll
        for (int r = 0; r < 4; ++r) { aN0[r] += g1N0*d0[r]; aN1[r] += g1N1*d1[r]; }
      }
    }
    {
      Seg s2 = s1;
      const bool cross1 = adv(s2);
      if (cross1) flushSeg(s1);
      s = s2;
    }
    if (more) {
#pragma unroll
      for (int qq = 0; qq < 4; ++qq)
        *(uint4*)&abuf[nb][(wave*4 + qq)*512 + lane*8] = pre[qq];
    }
    __syncthreads();
  }
  if (s.tt > 0) flushSeg(s);
}

// ============================ K4: per-edge epilogue + wenv; atomics straight into out
__global__ __launch_bounds__(256)
void k4_epi(const float* __restrict__ oa_g, const float* __restrict__ Rm,
            const float* __restrict__ D2bm,
            const float* __restrict__ lat, const float* __restrict__ WenvT,
            const int* __restrict__ eidx, const int* __restrict__ act,
            const float* __restrict__ Wp0, const float* __restrict__ bp0,
            const float* __restrict__ Wp1, const float* __restrict__ Wp2,
            float* __restrict__ out) {
  __shared__ float sc[4][200];  // gates 0..55 | y1g 56..103 | y2g 104..143 | we 144..199
  const int wave = threadIdx.x >> 6, lane = threadIdx.x & 63;
  const int eg = blockIdx.x*4 + wave;
  const int ae = act[eg];
  const float* o_ = oa_g + (size_t)eg*144;
  if (lane < 56) {
    const float4* wv = (const float4*)(WenvT + lane*128);
    const float4* lv = (const float4*)(lat + (size_t)ae*128);
    float4 s4 = {0,0,0,0};
#pragma unroll
    for (int l4 = 0; l4 < 32; ++l4) {
      float4 a = lv[l4], b = wv[l4];
      s4.x += a.x*b.x; s4.y += a.y*b.y; s4.z += a.z*b.z; s4.w += a.w*b.w;
    }
    sc[wave][144 + lane] = (s4.x + s4.y + s4.z + s4.w) * INV_SQRT128;
    float v = o_[lane];
    sc[wave][lane] = (lane < 32) ? v/(1.f + expf(-v)) : 1.f/(1.f + expf(-v));
  }
  __syncthreads();
  const float* Rr = Rm + (size_t)eg*9;
  const float* Db = D2bm + (size_t)eg*25;
  if (lane < 48) {
    int u = lane/3, cc = lane - u*3;
    float yx = o_[104+u], yy = o_[56+u], yz = o_[80+u];
    float p = Rr[cc]*yx + Rr[3+cc]*yy + Rr[6+cc]*yz;
    sc[wave][56+lane] = p * sc[wave][32+u];
  }
  __syncthreads();
  if (lane < 40) {
    int u = lane/5, ii = lane - u*5;
    float y0 = o_[136+u], y1v = o_[120+u], y2v = o_[72+u], y3 = o_[96+u], y4 = o_[128+u];
    float p = Db[ii*5+0]*y0 + Db[ii*5+1]*y1v + Db[ii*5+2]*y2v + Db[ii*5+3]*y3 + Db[ii*5+4]*y4;
    sc[wave][104+lane] = p * sc[wave][48+u];
  }
  __syncthreads();
  const int ctr = eidx[ae];
  float* dst = out + (size_t)ctr*120;
  const float* we = &sc[wave][144];
#pragma unroll
  for (int rnd = 0; rnd < 2; ++rnd) {
    int jo = rnd*64 + lane;
    if (jo < 120) {
      float val;
      if (jo < 32) {
        float s = 0.f;
#pragma unroll
        for (int i2 = 0; i2 < 32; ++i2) s += sc[wave][i2]*Wp0[i2*32 + jo];
        val = (s*INV_SQRT32 + bp0[jo]) * we[jo];
      } else if (jo < 80) {
        int jj = jo-32, v = jj/3, cc = jj - v*3;
        float s = 0.f;
#pragma unroll
        for (int u = 0; u < 16; ++u) s += sc[wave][56 + u*3 + cc]*Wp1[u*16 + v];
        val = s*INV_SQRT16*we[32+v];
      } else {
        int jj = jo-80, v = jj/5, ii = jj - v*5;
        float s = 0.f;
#pragma unroll
        for (int u = 0; u < 8; ++u) s += sc[wave][104 + u*5 + ii]*Wp2[u*8 + v];
        val = s*INV_SQRT8*we[48+v];
      }
      atomicAdd(&dst[jo], OUTSC*val);
    }
  }
}

// ---------------------------------------------------------------- launcher
extern "C" void kernel_launch(void* const* d_in, const int* in_sizes, int n_in,
                              void* d_out, int out_size, void* d_ws, size_t ws_size,
                              hipStream_t stream) {
  const float* lat  = (const float*)d_in[0];
  const float* ndf  = (const float*)d_in[1];
  const float* hid  = (const float*)d_in[2];
  const float* evec = (const float*)d_in[4];
  const float* Wtp  = (const float*)d_in[5];
  const float* Wenv = (const float*)d_in[6];
  const float* w0   = (const float*)d_in[7];
  const float* b0   = (const float*)d_in[8];
  const float* w1   = (const float*)d_in[9];
  const float* w2   = (const float*)d_in[10];
  const float* Wp0  = (const float*)d_in[11];
  const float* bp0  = (const float*)d_in[12];
  const float* Wp1  = (const float*)d_in[13];
  const float* Wp2  = (const float*)d_in[14];
  const float* Wr0  = (const float*)d_in[15];
  const float* br0  = (const float*)d_in[16];
  const float* Wr1  = (const float*)d_in[17];
  const float* Wr2  = (const float*)d_in[18];
  const int*   eidx = (const int*)d_in[20];
  const int*   act  = (const int*)d_in[21];
  float* out = (float*)d_out;

  char* p = (char*)d_ws;
  float*    invT  = (float*)(p + 245760);              // 9,830,400
  float*    Rm    = (float*)(p + 10076160);            // 368,640
  float*    D2bm  = (float*)(p + 10444800);            // 1,024,000
  float*    oa_g  = (float*)(p + 14008320);            // 5,898,240
  ushort_t* lath  = (ushort_t*)(p + 19906560);         // 2,621,440
  ushort_t* latl  = (ushort_t*)(p + 22528000);         // 2,621,440
  ushort_t* Wpack = (ushort_t*)(p + 25149440);         // 5,898,240
  float*    WenvT = (float*)(p + 31047680);            // 28,672 (end 31,076,352)

  kAB<<<6672, 256, 0, stream>>>(Wtp, lat, Wenv, ndf, hid, evec, eidx, act,
                                w0, b0, w1, w2, Wr0, br0, Wr1, Wr2,
                                Wpack, lath, latl, oa_g, WenvT, invT, Rm, D2bm, out);
  k3_gemm<<<dim3(E_TOT/128, 9), 256, 0, stream>>>(Wpack, lath, latl, invT, oa_g);
  k4_epi<<<E_TOT/4, 256, 0, stream>>>(oa_g, Rm, D2bm, lat, WenvT, eidx, act,
                                      Wp0, bp0, Wp1, Wp2, out);
}

// Round 9
// 284.196 us; speedup vs baseline: 1.3662x; 1.0674x over previous
//
#include <hip/hip_runtime.h>
#include <math.h>

#define E_TOT   10240
#define N_NODES 512
#define NCOL    11520

typedef unsigned short ushort_t;
typedef unsigned int   uint_t;
typedef __bf16 bf16x8 __attribute__((ext_vector_type(8)));
typedef float  f32x4  __attribute__((ext_vector_type(4)));

constexpr float EPSF        = 1e-5f;
constexpr float INV_SQRT128 = 0.08838834764831845f;
constexpr float INV_SQRT112 = 0.09449111825230681f;
constexpr float INV_SQRT48  = 0.14433756729740643f;
constexpr float INV_SQRT32  = 0.17677669529663687f;
constexpr float INV_SQRT16  = 0.25f;
constexpr float INV_SQRT8   = 0.35355339059327373f;
constexpr float SC0 = INV_SQRT128 * INV_SQRT112;
constexpr float SC1 = INV_SQRT128 * INV_SQRT48;
constexpr float SC2 = INV_SQRT128 * INV_SQRT16;
constexpr float C_OLD_ = 0.8944271909999159f;
constexpr float C_NEW_ = 0.4472135954999579f;
constexpr float NORMC  = 0.22360679774997896f;
constexpr float OUTSC  = C_NEW_ * NORMC;

// ---------------------------------------------------------------- utilities
__device__ __forceinline__ ushort_t f2bf(float x) {
  uint_t u = __float_as_uint(x);
  u = (u + 0x7fffu + ((u >> 16) & 1u)) >> 16;
  return (ushort_t)u;
}

// Analytic Wigner-D (l=2) in basis {xy, yz, 3z^2-1, xz, x^2-y^2}.
__device__ __forceinline__ void wigner5(const float q[9], float D[25]) {
  const float q0x=q[0],q0y=q[1],q0z=q[2];
  const float q1x=q[3],q1y=q[4],q1z=q[5];
  const float q2x=q[6],q2y=q[7],q2z=q[8];
  D[0]  = q0x*q1y + q1x*q0y;
  D[1]  = q0y*q1z + q1y*q0z;
  D[2]  = 0.5f*(q0z*q1z);
  D[3]  = q0x*q1z + q1x*q0z;
  D[4]  = 0.5f*(q0x*q1x - q0y*q1y);
  D[5]  = q1x*q2y + q2x*q1y;
  D[6]  = q1y*q2z + q2y*q1z;
  D[7]  = 0.5f*(q1z*q2z);
  D[8]  = q1x*q2z + q2x*q1z;
  D[9]  = 0.5f*(q1x*q2x - q1y*q2y);
  D[10] = 6.f*q2x*q2y;
  D[11] = 6.f*q2y*q2z;
  D[12] = 0.5f*(3.f*q2z*q2z - 1.f);
  D[13] = 6.f*q2x*q2z;
  D[14] = 1.5f*(q2x*q2x - q2y*q2y);
  D[15] = q0x*q2y + q2x*q0y;
  D[16] = q0y*q2z + q2y*q0z;
  D[17] = 0.5f*(q0z*q2z);
  D[18] = q0x*q2z + q2x*q0z;
  D[19] = 0.5f*(q0x*q2x - q0y*q2y);
  D[20] = 2.f*(q0x*q0y - q1x*q1y);
  D[21] = 2.f*(q0y*q0z - q1y*q1z);
  D[22] = 0.5f*(q0z*q0z - q1z*q1z);
  D[23] = 2.f*(q0x*q0z - q1x*q1z);
  D[24] = 0.5f*((q0x*q0x - q1x*q1x) - (q0y*q0y - q1y*q1y));
}

// ============================ kAB: all independent prep work in ONE dispatch
// bid [0,720)        : pack W_tp tile -> contiguous-c MFMA bf16 hi/lo fragments
// bid [720,5840)     : j=bid-720: latpack 256 elems; zero 288 oa_g
// bid [5840,6160)    : edge-prep (sln + frames + Wigner + so2 inputs), 32 edges
// bid [6160,6672)    : residual init: out[n] = C_OLD * ir_linear(ndf)[n]
// bid [6672,6712)    : wenv = lat[act[e]] @ Wenv / sqrt(128), 256 edges/block
__global__ __launch_bounds__(256)
void kAB(const float* __restrict__ Wtp, const float* __restrict__ lat,
         const float* __restrict__ Wenv,
         const float* __restrict__ ndf, const float* __restrict__ hid,
         const float* __restrict__ evec,
         const int* __restrict__ eidx, const int* __restrict__ act,
         const float* __restrict__ w0, const float* __restrict__ b0,
         const float* __restrict__ w1, const float* __restrict__ w2,
         const float* __restrict__ Wr0, const float* __restrict__ br0,
         const float* __restrict__ Wr1, const float* __restrict__ Wr2,
         ushort_t* __restrict__ Wp,
         ushort_t* __restrict__ lath, ushort_t* __restrict__ latl,
         float* __restrict__ oa_g, float* __restrict__ wenvg,
         float* __restrict__ invT, float* __restrict__ Rm,
         float* __restrict__ D2bm, float* __restrict__ out) {
  __shared__ __align__(16) char smem[47104];
  const int bid = blockIdx.x;
  const int t = threadIdx.x;
  if (bid < 720) {
    // ---------------- W_tp pack (coalesced via LDS transpose)
    float* Wl = (float*)smem;           // [l][m] pad 17
    const int nt = bid;
    int col, tt;
    if (nt < 560)      { col = nt/112; tt = nt - col*112; }
    else if (nt < 608) { col = 5;  tt = nt-560; }
    else if (nt < 632) { col = 6;  tt = nt-608; }
    else if (nt < 680) { col = 7;  tt = nt-632; }
    else if (nt < 704) { col = 8;  tt = nt-680; }
    else if (nt < 712) { col = 9;  tt = nt-704; }
    else               { col = 10; tt = nt-712; }
    {
      const int m1 = t & 15, lp = t >> 4;
      int c; float sc;
      switch (col) {
        case 5:  c = 8960  + tt*24 + m1;                        sc = SC1; break;
        case 6:  c = 8960  + (2*tt + (m1>>3))*24 + 16 + (m1&7); sc = SC1; break;
        case 7:  c = 10112 + tt*24 + m1;                        sc = SC1; break;
        case 8:  c = 10112 + (2*tt + (m1>>3))*24 + 16 + (m1&7); sc = SC1; break;
        case 9:  c = 11264 + (2*tt + (m1>>3))*8 + (m1&7);       sc = SC2; break;
        case 10: c = 11392 + (2*tt + (m1>>3))*8 + (m1&7);       sc = SC2; break;
        default: c = tt*80 + col*16 + m1;                       sc = SC0; break;
      }
#pragma unroll
      for (int p = 0; p < 8; ++p) {
        int l = p*16 + lp;
        Wl[l*17 + m1] = Wtp[(size_t)l*NCOL + c] * sc;
      }
    }
    __syncthreads();
    const int kc = t >> 6, lane = t & 63;
    const int m = lane & 15, kg = lane >> 4;
    ushort_t hi[8], lo[8];
#pragma unroll
    for (int jj = 0; jj < 8; ++jj) {
      int l = kc*32 + kg*8 + jj;
      float w = Wl[l*17 + m];
      ushort_t h = f2bf(w);
      float hf = __uint_as_float(((uint_t)h) << 16);
      hi[jj] = h;
      lo[jj] = f2bf(w - hf);
    }
    size_t base = ((size_t)nt*8 + kc*2)*512 + (size_t)lane*8;
    *(uint4*)&Wp[base]       = *(const uint4*)hi;
    *(uint4*)&Wp[base + 512] = *(const uint4*)lo;
    return;
  }
  if (bid < 5840) {
    // ---------------- latpack + zero oa_g
    const int j = bid - 720;                 // 0..5119
    const int idx = j*256 + t;
    float x = lat[idx];
    ushort_t h = f2bf(x);
    float hf = __uint_as_float(((uint_t)h) << 16);
    lath[idx] = h;
    latl[idx] = f2bf(x - hf);
#pragma unroll
    for (int i = t; i < 288; i += 256) oa_g[(size_t)j*288 + i] = 0.f;
    return;
  }
  if (bid < 6160) {
    // ---------------- edge prep (sln fused), 32 edges
    float (*xs)[240] = (float(*)[240])smem;                 // 30720
    float (*Rs)[9]   = (float(*)[9])(smem + 30720);         // 1152
    float (*Dfs)[25] = (float(*)[25])(smem + 31872);        // 3200
    float* muS  = (float*)(smem + 35072);
    float* isS  = (float*)(smem + 35200);
    float* invS = (float*)(smem + 35328);
    int*   ctrs = (int*)(smem + 35456);
    const int e0 = (bid - 5840)*32;
    if (t < 32) {
      const int e = e0 + t;
      const int ae = act[e];
      ctrs[t] = eidx[ae];
      float vx = evec[ae*3+0], vy = evec[ae*3+1], vz = evec[ae*3+2];
      float rn = rsqrtf(vx*vx + vy*vy + vz*vz);
      float nx = vx*rn, ny = vy*rn, nz = vz*rn;
      float e1x, e1y, e1z;
      if (fabsf(nz) < 0.99f) { e1x = -ny; e1y = nx;  e1z = 0.f; }
      else                   { e1x = 0.f; e1y = -nz; e1z = ny;  }
      float rl = rsqrtf(e1x*e1x + e1y*e1y + e1z*e1z);
      e1x *= rl; e1y *= rl; e1z *= rl;
      float e2x = ny*e1z - nz*e1y;
      float e2y = nz*e1x - nx*e1z;
      float e2z = nx*e1y - ny*e1x;
      float R[9] = {e1x,e1y,e1z, e2x,e2y,e2z, nx,ny,nz};
#pragma unroll
      for (int jj = 0; jj < 9; ++jj) { Rs[t][jj] = R[jj]; Rm[(size_t)e*9 + jj] = R[jj]; }
      float Df[25];
      wigner5(R, Df);
#pragma unroll
      for (int jj = 0; jj < 25; ++jj) Dfs[t][jj] = Df[jj];
      float Rt[9] = {R[0],R[3],R[6], R[1],R[4],R[7], R[2],R[5],R[8]};
      float Db[25];
      wigner5(Rt, Db);
#pragma unroll
      for (int jj = 0; jj < 25; ++jj) D2bm[(size_t)e*25 + jj] = Db[jj];
    }
    __syncthreads();
    for (int i = t; i < 32*120; i += 256) {
      int s = i/120, jj = i - s*120;
      xs[s][jj]     = ndf[(size_t)ctrs[s]*120 + jj];
      xs[s][120+jj] = hid[(size_t)(e0+s)*120 + jj];
    }
    __syncthreads();
    if (t < 32) {
      float sum = 0.f, sq = 0.f;
#pragma unroll
      for (int i = 0; i < 32; ++i) { float v = xs[t][i]; sum += v; sq += v*v; }
      float mu = sum*(1.f/32.f);
      float var = sq*(1.f/32.f) - mu*mu;
      float v1s = 0.f, v2s = 0.f;
#pragma unroll
      for (int i = 32; i < 80; ++i) { float v = xs[t][i]; v1s += v*v; }
#pragma unroll
      for (int i = 80; i < 120; ++i) { float v = xs[t][i]; v2s += v*v; }
      muS[t] = mu;
      isS[t] = rsqrtf(var + EPSF);
      invS[t] = rsqrtf(0.5f*(v1s*(1.f/48.f) + v2s*(1.f/40.f)) + EPSF);
    }
    __syncthreads();
    const int e = t & 31, rb = t >> 5;
    const float* X  = xs[e];
    const float* Rr = Rs[e];
    const float* Df = Dfs[e];
    const float mu = muS[e], istd = isS[e], inv = invS[e];
#pragma unroll
    for (int r = rb; r < 240; r += 8) {
      float val;
      if (r < 64) {
        if (r < 32) val = (X[r] - mu)*istd*w0[r] + b0[r];
        else        val = X[88 + r];
      } else if (r < 96) {
        int u = r - 64; int b; float fac;
        if (u < 16) { b = 32 + 3*u; fac = inv*w1[u]; } else { b = 152 + 3*(u-16); fac = 1.f; }
        val = (Rr[3]*X[b] + Rr[4]*X[b+1] + Rr[5]*X[b+2])*fac;
      } else if (r < 112) {
        int u = r - 96; int b; float fac;
        if (u < 8) { b = 80 + 5*u; fac = inv*w2[u]; } else { b = 200 + 5*(u-8); fac = 1.f; }
        val = (Df[10]*X[b] + Df[11]*X[b+1] + Df[12]*X[b+2] + Df[13]*X[b+3] + Df[14]*X[b+4])*fac;
      } else if (r < 160) {
        int u = r - 112;
        if (u < 32) {
          int b; float fac;
          if (u < 16) { b = 32 + 3*u; fac = inv*w1[u]; } else { b = 152 + 3*(u-16); fac = 1.f; }
          val = (Rr[0]*X[b] + Rr[1]*X[b+1] + Rr[2]*X[b+2])*fac;
        } else {
          int u2 = u - 32; int b; float fac;
          if (u2 < 8) { b = 80 + 5*u2; fac = inv*w2[u2]; } else { b = 200 + 5*(u2-8); fac = 1.f; }
          val = (Df[5]*X[b] + Df[6]*X[b+1] + Df[7]*X[b+2] + Df[8]*X[b+3] + Df[9]*X[b+4])*fac;
        }
      } else if (r < 208) {
        int u = r - 160;
        if (u < 32) {
          int b; float fac;
          if (u < 16) { b = 32 + 3*u; fac = inv*w1[u]; } else { b = 152 + 3*(u-16); fac = 1.f; }
          val = (Rr[6]*X[b] + Rr[7]*X[b+1] + Rr[8]*X[b+2])*fac;
        } else {
          int u2 = u - 32; int b; float fac;
          if (u2 < 8) { b = 80 + 5*u2; fac = inv*w2[u2]; } else { b = 200 + 5*(u2-8); fac = 1.f; }
          val = (Df[15]*X[b] + Df[16]*X[b+1] + Df[17]*X[b+2] + Df[18]*X[b+3] + Df[19]*X[b+4])*fac;
        }
      } else if (r < 224) {
        int u = r - 208; int b; float fac;
        if (u < 8) { b = 80 + 5*u; fac = inv*w2[u]; } else { b = 200 + 5*(u-8); fac = 1.f; }
        val = (Df[0]*X[b] + Df[1]*X[b+1] + Df[2]*X[b+2] + Df[3]*X[b+3] + Df[4]*X[b+4])*fac;
      } else {
        int u = r - 224; int b; float fac;
        if (u < 8) { b = 80 + 5*u; fac = inv*w2[u]; } else { b = 200 + 5*(u-8); fac = 1.f; }
        val = (Df[20]*X[b] + Df[21]*X[b+1] + Df[22]*X[b+2] + Df[23]*X[b+3] + Df[24]*X[b+4])*fac;
      }
      invT[(size_t)r*E_TOT + e0 + e] = val;
    }
    return;
  }
  if (bid < 6672) {
    // ---------------- residual init: out = C_OLD * ir_linear(ndf)
    const int n = bid - 6160;
    if (t >= 120) return;
    const float* x = ndf + (size_t)n*120;
    float r;
    if (t < 32) {
      float s = 0.f;
#pragma unroll
      for (int i = 0; i < 32; ++i) s += x[i]*Wr0[i*32 + t];
      r = s*INV_SQRT32 + br0[t];
    } else if (t < 80) {
      int j = t - 32, v = j/3, cp = j - 3*v;
      float s = 0.f;
#pragma unroll
      for (int u = 0; u < 16; ++u) s += x[32 + u*3 + cp]*Wr1[u*16 + v];
      r = s*INV_SQRT16;
    } else {
      int j = t - 80, v = j/5, cp = j - 5*v;
      float s = 0.f;
#pragma unroll
      for (int u = 0; u < 8; ++u) s += x[80 + u*5 + cp]*Wr2[u*8 + v];
      r = s*INV_SQRT8;
    }
    out[(size_t)n*120 + t] = C_OLD_*r;
    return;
  }
  // ---------------- wenv: 256 edges/block, Wenv in LDS (broadcast rows)
  {
    float* Wl2  = (float*)smem;              // 128*56 = 28672 B
    float* latc = (float*)(smem + 28672);    // 256*17 floats = 17408 B
    int*   aes  = (int*)(smem + 46080);      // 1024 B
    const int e0 = (bid - 6672)*256;
    for (int i = t; i < 128*56; i += 256) Wl2[i] = Wenv[i];
    aes[t] = act[e0 + t];
    float acc[56];
#pragma unroll
    for (int o = 0; o < 56; ++o) acc[o] = 0.f;
    for (int lc = 0; lc < 8; ++lc) {
      __syncthreads();
      for (int i = t; i < 256*16; i += 256) {
        int el = i >> 4, j = i & 15;
        latc[el*17 + j] = lat[(size_t)aes[el]*128 + lc*16 + j];
      }
      __syncthreads();
#pragma unroll
      for (int j = 0; j < 16; ++j) {
        float lv = latc[t*17 + j];
        const float* wr = &Wl2[(lc*16 + j)*56];
#pragma unroll
        for (int o = 0; o < 56; ++o) acc[o] += lv * wr[o];
      }
    }
    float* dst = wenvg + (size_t)(e0 + t)*56;
#pragma unroll
    for (int o = 0; o < 56; ++o) dst[o] = acc[o] * INV_SQRT128;
  }
}

// ============================ K3: MFMA GEMM (R4 shape + split acc + chunk-ahead gathers)
struct Seg { int col, tt, mP, mN, sP, sN, segLen; float sg; bool PAIR, TWO; };
__device__ __forceinline__ void setp(Seg& s) {
  const int cf = s.col;
  if (cf < 5)       { s.segLen=112; s.mP=0;   s.mN=0;   s.sP=cf*16; s.sN=0;   s.sg=1.f;  s.PAIR=false; s.TWO=false; }
  else if (cf == 5) { s.segLen=48;  s.mP=160; s.mN=112; s.sP=80;  s.sN=104; s.sg=1.f;  s.PAIR=false; s.TWO=true; }
  else if (cf == 6) { s.segLen=24;  s.mP=160; s.mN=112; s.sP=96;  s.sN=120; s.sg=1.f;  s.PAIR=true;  s.TWO=true; }
  else if (cf == 7) { s.segLen=48;  s.mP=112; s.mN=160; s.sP=80;  s.sN=104; s.sg=-1.f; s.PAIR=false; s.TWO=true; }
  else if (cf == 8) { s.segLen=24;  s.mP=112; s.mN=160; s.sP=96;  s.sN=120; s.sg=-1.f; s.PAIR=true;  s.TWO=true; }
  else if (cf == 9) { s.segLen=8;   s.mP=224; s.mN=208; s.sP=128; s.sN=136; s.sg=1.f;  s.PAIR=true;  s.TWO=true; }
  else              { s.segLen=8;   s.mP=208; s.mN=224; s.sP=128; s.sN=136; s.sg=-1.f; s.PAIR=true;  s.TWO=true; }
}
__device__ __forceinline__ bool adv(Seg& s) {
  s.tt++;
  if (s.tt == s.segLen) { s.col++; s.tt = 0; setp(s); return true; }
  return false;
}

__global__ __launch_bounds__(256, 3)
void k3_gemm(const ushort_t* __restrict__ Wp,
             const ushort_t* __restrict__ lath,
             const ushort_t* __restrict__ latl,
             const float*  __restrict__ invT,
             float* __restrict__ oa_g) {
  __shared__ __align__(16) ushort_t abuf[2][8192];   // 2 x (2 tiles x 8 frags x 512)
  const int t = threadIdx.x;
  const int wave = t >> 6, lane = t & 63;
  const int le = lane & 15, g = lane >> 4, gh = g >> 1;
  const int fbase = blockIdx.y * 80;
  const int e0w = blockIdx.x*128 + wave*32;
  // ---- B fragments (wave's 32 edges)
  bf16x8 Bh[4][2], Bl[4][2];
#pragma unroll
  for (int kc = 0; kc < 4; ++kc)
#pragma unroll
    for (int n = 0; n < 2; ++n) {
      size_t off = (size_t)(e0w + n*16 + le)*128 + kc*32 + g*8;
      Bh[kc][n] = *(const bf16x8*)(lath + off);
      Bl[kc][n] = *(const bf16x8*)(latl + off);
    }
  // ---- segment state
  Seg s;
  if (fbase < 560)      { s.col = fbase/112; s.tt = fbase - s.col*112; }
  else if (fbase < 608) { s.col = 5;  s.tt = fbase-560; }
  else if (fbase < 632) { s.col = 6;  s.tt = fbase-608; }
  else if (fbase < 680) { s.col = 7;  s.tt = fbase-632; }
  else if (fbase < 704) { s.col = 8;  s.tt = fbase-680; }
  else if (fbase < 712) { s.col = 9;  s.tt = fbase-704; }
  else                  { s.col = 10; s.tt = fbase-712; }
  setp(s);
  auto loadG = [&](const Seg& q, float& p0, float& p1, float& n0, float& n1) {
    int idx = q.PAIR ? (2*q.tt + gh) : q.tt;
    p0 = invT[(size_t)(q.mP + idx)*E_TOT + e0w + le];
    p1 = invT[(size_t)(q.mP + idx)*E_TOT + e0w + 16 + le];
    if (q.TWO) {
      n0 = invT[(size_t)(q.mN + idx)*E_TOT + e0w + le];
      n1 = invT[(size_t)(q.mN + idx)*E_TOT + e0w + 16 + le];
    } else { n0 = 0.f; n1 = 0.f; }
  };
  f32x4 aP0={0,0,0,0}, aP1={0,0,0,0}, aN0={0,0,0,0}, aN1={0,0,0,0};
  auto flushSeg = [&](const Seg& fs) {
#pragma unroll
    for (int r = 0; r < 4; ++r) {
      int mm = g*4 + r;
      int sp = fs.sP + (fs.PAIR ? (mm & 7) : mm);
      atomicAdd(&oa_g[(size_t)(e0w + le)*144 + sp], fs.sg*aP0[r]);
      atomicAdd(&oa_g[(size_t)(e0w + 16 + le)*144 + sp], fs.sg*aP1[r]);
      if (fs.TWO) {
        int sn = fs.sN + (fs.PAIR ? (mm & 7) : mm);
        atomicAdd(&oa_g[(size_t)(e0w + le)*144 + sn], aN0[r]);
        atomicAdd(&oa_g[(size_t)(e0w + 16 + le)*144 + sn], aN1[r]);
      }
    }
    aP0 = (f32x4){0,0,0,0}; aP1 = (f32x4){0,0,0,0};
    aN0 = (f32x4){0,0,0,0}; aN1 = (f32x4){0,0,0,0};
  };
  // ---- stage chunk 0 + gathers for chunk 0
#pragma unroll
  for (int qq = 0; qq < 4; ++qq) {
    uint4 v = *(const uint4*)(Wp + ((size_t)fbase*8 + wave*4 + qq)*512 + lane*8);
    *(uint4*)&abuf[0][(wave*4 + qq)*512 + lane*8] = v;
  }
  float cP0[2], cP1[2], cN0[2], cN1[2];
  {
    Seg t0 = s; Seg t1 = s; adv(t1);
    loadG(t0, cP0[0], cP1[0], cN0[0], cN1[0]);
    loadG(t1, cP0[1], cP1[1], cN0[1], cN1[1]);
  }
  __syncthreads();
  // ---- main loop: 40 chunks of 2 tiles
  for (int c = 0; c < 40; ++c) {
    const int cb = c & 1, nb = cb ^ 1;
    uint4 pre[4];
    const bool more = (c + 1) < 40;
    float nP0[2], nP1[2], nN0[2], nN1[2];
    if (more) {
#pragma unroll
      for (int qq = 0; qq < 4; ++qq)
        pre[qq] = *(const uint4*)(Wp + ((size_t)(fbase + 2*(c+1))*8 + wave*4 + qq)*512 + lane*8);
      Seg t0 = s; adv(t0); adv(t0);     // tile 0 of next chunk
      Seg t1 = t0; adv(t1);             // tile 1 of next chunk
      loadG(t0, nP0[0], nP1[0], nN0[0], nN1[0]);
      loadG(t1, nP0[1], nP1[1], nN0[1], nN1[1]);
    }
    // ---- tile 0: split accumulators, 4 independent chains
    Seg s1 = s;
    const bool cross0 = adv(s1);
    {
      f32x4 dE0={0,0,0,0}, dO0={0,0,0,0}, dE1={0,0,0,0}, dO1={0,0,0,0};
#pragma unroll
      for (int kc = 0; kc < 2; ++kc) {
        bf16x8 Ah = *(const bf16x8*)&abuf[cb][(kc*2 + 0)*512 + lane*8];
        bf16x8 Al = *(const bf16x8*)&abuf[cb][(kc*2 + 1)*512 + lane*8];
        dE0 = __builtin_amdgcn_mfma_f32_16x16x32_bf16(Ah, Bh[kc][0], dE0, 0, 0, 0);
        dE1 = __builtin_amdgcn_mfma_f32_16x16x32_bf16(Ah, Bh[kc][1], dE1, 0, 0, 0);
        dE0 = __builtin_amdgcn_mfma_f32_16x16x32_bf16(Ah, Bl[kc][0], dE0, 0, 0, 0);
        dE1 = __builtin_amdgcn_mfma_f32_16x16x32_bf16(Ah, Bl[kc][1], dE1, 0, 0, 0);
        dE0 = __builtin_amdgcn_mfma_f32_16x16x32_bf16(Al, Bh[kc][0], dE0, 0, 0, 0);
        dE1 = __builtin_amdgcn_mfma_f32_16x16x32_bf16(Al, Bh[kc][1], dE1, 0, 0, 0);
      }
#pragma unroll
      for (int kc = 2; kc < 4; ++kc) {
        bf16x8 Ah = *(const bf16x8*)&abuf[cb][(kc*2 + 0)*512 + lane*8];
        bf16x8 Al = *(const bf16x8*)&abuf[cb][(kc*2 + 1)*512 + lane*8];
        dO0 = __builtin_amdgcn_mfma_f32_16x16x32_bf16(Ah, Bh[kc][0], dO0, 0, 0, 0);
        dO1 = __builtin_amdgcn_mfma_f32_16x16x32_bf16(Ah, Bh[kc][1], dO1, 0, 0, 0);
        dO0 = __builtin_amdgcn_mfma_f32_16x16x32_bf16(Ah, Bl[kc][0], dO0, 0, 0, 0);
        dO1 = __builtin_amdgcn_mfma_f32_16x16x32_bf16(Ah, Bl[kc][1], dO1, 0, 0, 0);
        dO0 = __builtin_amdgcn_mfma_f32_16x16x32_bf16(Al, Bh[kc][0], dO0, 0, 0, 0);
        dO1 = __builtin_amdgcn_mfma_f32_16x16x32_bf16(Al, Bh[kc][1], dO1, 0, 0, 0);
      }
      f32x4 d0 = dE0 + dO0, d1 = dE1 + dO1;
#pragma unroll
      for (int r = 0; r < 4; ++r) { aP0[r] += cP0[0]*d0[r]; aP1[r] += cP1[0]*d1[r]; }
      if (s.TWO) {
#pragma unroll
        for (int r = 0; r < 4; ++r) { aN0[r] += cN0[0]*d0[r]; aN1[r] += cN1[0]*d1[r]; }
      }
    }
    if (cross0) flushSeg(s);
    // ---- tile 1
    {
      f32x4 dE0={0,0,0,0}, dO0={0,0,0,0}, dE1={0,0,0,0}, dO1={0,0,0,0};
#pragma unroll
      for (int kc = 0; kc < 2; ++kc) {
        bf16x8 Ah = *(const bf16x8*)&abuf[cb][(8 + kc*2 + 0)*512 + lane*8];
        bf16x8 Al = *(const bf16x8*)&abuf[cb][(8 + kc*2 + 1)*512 + lane*8];
        dE0 = __builtin_amdgcn_mfma_f32_16x16x32_bf16(Ah, Bh[kc][0], dE0, 0, 0, 0);
        dE1 = __builtin_amdgcn_mfma_f32_16x16x32_bf16(Ah, Bh[kc][1], dE1, 0, 0, 0);
        dE0 = __builtin_amdgcn_mfma_f32_16x16x32_bf16(Ah, Bl[kc][0], dE0, 0, 0, 0);
        dE1 = __builtin_amdgcn_mfma_f32_16x16x32_bf16(Ah, Bl[kc][1], dE1, 0, 0, 0);
        dE0 = __builtin_amdgcn_mfma_f32_16x16x32_bf16(Al, Bh[kc][0], dE0, 0, 0, 0);
        dE1 = __builtin_amdgcn_mfma_f32_16x16x32_bf16(Al, Bh[kc][1], dE1, 0, 0, 0);
      }
#pragma unroll
      for (int kc = 2; kc < 4; ++kc) {
        bf16x8 Ah = *(const bf16x8*)&abuf[cb][(8 + kc*2 + 0)*512 + lane*8];
        bf16x8 Al = *(const bf16x8*)&abuf[cb][(8 + kc*2 + 1)*512 + lane*8];
        dO0 = __builtin_amdgcn_mfma_f32_16x16x32_bf16(Ah, Bh[kc][0], dO0, 0, 0, 0);
        dO1 = __builtin_amdgcn_mfma_f32_16x16x32_bf16(Ah, Bh[kc][1], dO1, 0, 0, 0);
        dO0 = __builtin_amdgcn_mfma_f32_16x16x32_bf16(Ah, Bl[kc][0], dO0, 0, 0, 0);
        dO1 = __builtin_amdgcn_mfma_f32_16x16x32_bf16(Ah, Bl[kc][1], dO1, 0, 0, 0);
        dO0 = __builtin_amdgcn_mfma_f32_16x16x32_bf16(Al, Bh[kc][0], dO0, 0, 0, 0);
        dO1 = __builtin_amdgcn_mfma_f32_16x16x32_bf16(Al, Bh[kc][1], dO1, 0, 0, 0);
      }
      f32x4 d0 = dE0 + dO0, d1 = dE1 + dO1;
#pragma unroll
      for (int r = 0; r < 4; ++r) { aP0[r] += cP0[1]*d0[r]; aP1[r] += cP1[1]*d1[r]; }
      if (s1.TWO) {
#pragma unroll
        for (int r = 0; r < 4; ++r) { aN0[r] += cN0[1]*d0[r]; aN1[r] += cN1[1]*d1[r]; }
      }
    }
    {
      Seg s2 = s1;
      const bool cross1 = adv(s2);
      if (cross1) flushSeg(s1);
      s = s2;
    }
#pragma unroll
    for (int q2 = 0; q2 < 2; ++q2) {
      cP0[q2] = nP0[q2]; cP1[q2] = nP1[q2];
      cN0[q2] = nN0[q2]; cN1[q2] = nN1[q2];
    }
    if (more) {
#pragma unroll
      for (int qq = 0; qq < 4; ++qq)
        *(uint4*)&abuf[nb][(wave*4 + qq)*512 + lane*8] = pre[qq];
    }
    __syncthreads();
  }
  if (s.tt > 0) flushSeg(s);
}

// ============================ K4: per-edge epilogue; wenv precomputed; atomics into out
__global__ __launch_bounds__(256)
void k4_epi(const float* __restrict__ oa_g, const float* __restrict__ Rm,
            const float* __restrict__ D2bm, const float* __restrict__ wenvg,
            const int* __restrict__ eidx, const int* __restrict__ act,
            const float* __restrict__ Wp0, const float* __restrict__ bp0,
            const float* __restrict__ Wp1, const float* __restrict__ Wp2,
            float* __restrict__ out) {
  __shared__ float sc[4][200];  // gates 0..55 | y1g 56..103 | y2g 104..143 | we 144..199
  const int wave = threadIdx.x >> 6, lane = threadIdx.x & 63;
  const int eg = blockIdx.x*4 + wave;
  const int ae = act[eg];
  const float* o_ = oa_g + (size_t)eg*144;
  if (lane < 56) {
    sc[wave][144 + lane] = wenvg[(size_t)eg*56 + lane];
    float v = o_[lane];
    sc[wave][lane] = (lane < 32) ? v/(1.f + expf(-v)) : 1.f/(1.f + expf(-v));
  }
  __syncthreads();
  const float* Rr = Rm + (size_t)eg*9;
  const float* Db = D2bm + (size_t)eg*25;
  if (lane < 48) {
    int u = lane/3, cc = lane - u*3;
    float yx = o_[104+u], yy = o_[56+u], yz = o_[80+u];
    float p = Rr[cc]*yx + Rr[3+cc]*yy + Rr[6+cc]*yz;
    sc[wave][56+lane] = p * sc[wave][32+u];
  }
  __syncthreads();
  if (lane < 40) {
    int u = lane/5, ii = lane - u*5;
    float y0 = o_[136+u], y1v = o_[120+u], y2v = o_[72+u], y3 = o_[96+u], y4 = o_[128+u];
    float p = Db[ii*5+0]*y0 + Db[ii*5+1]*y1v + Db[ii*5+2]*y2v + Db[ii*5+3]*y3 + Db[ii*5+4]*y4;
    sc[wave][104+lane] = p * sc[wave][48+u];
  }
  __syncthreads();
  const int ctr = eidx[ae];
  float* dst = out + (size_t)ctr*120;
  const float* we = &sc[wave][144];
#pragma unroll
  for (int rnd = 0; rnd < 2; ++rnd) {
    int jo = rnd*64 + lane;
    if (jo < 120) {
      float val;
      if (jo < 32) {
        float s = 0.f;
#pragma unroll
        for (int i2 = 0; i2 < 32; ++i2) s += sc[wave][i2]*Wp0[i2*32 + jo];
        val = (s*INV_SQRT32 + bp0[jo]) * we[jo];
      } else if (jo < 80) {
        int jj = jo-32, v = jj/3, cc = jj - v*3;
        float s = 0.f;
#pragma unroll
        for (int u = 0; u < 16; ++u) s += sc[wave][56 + u*3 + cc]*Wp1[u*16 + v];
        val = s*INV_SQRT16*we[32+v];
      } else {
        int jj = jo-80, v = jj/5, ii = jj - v*5;
        float s = 0.f;
#pragma unroll
        for (int u = 0; u < 8; ++u) s += sc[wave][104 + u*5 + ii]*Wp2[u*8 + v];
        val = s*INV_SQRT8*we[48+v];
      }
      atomicAdd(&dst[jo], OUTSC*val);
    }
  }
}

// ---------------------------------------------------------------- launcher
extern "C" void kernel_launch(void* const* d_in, const int* in_sizes, int n_in,
                              void* d_out, int out_size, void* d_ws, size_t ws_size,
                              hipStream_t stream) {
  const float* lat  = (const float*)d_in[0];
  const float* ndf  = (const float*)d_in[1];
  const float* hid  = (const float*)d_in[2];
  const float* evec = (const float*)d_in[4];
  const float* Wtp  = (const float*)d_in[5];
  const float* Wenv = (const float*)d_in[6];
  const float* w0   = (const float*)d_in[7];
  const float* b0   = (const float*)d_in[8];
  const float* w1   = (const float*)d_in[9];
  const float* w2   = (const float*)d_in[10];
  const float* Wp0  = (const float*)d_in[11];
  const float* bp0  = (const float*)d_in[12];
  const float* Wp1  = (const float*)d_in[13];
  const float* Wp2  = (const float*)d_in[14];
  const float* Wr0  = (const float*)d_in[15];
  const float* br0  = (const float*)d_in[16];
  const float* Wr1  = (const float*)d_in[17];
  const float* Wr2  = (const float*)d_in[18];
  const int*   eidx = (const int*)d_in[20];
  const int*   act  = (const int*)d_in[21];
  float* out = (float*)d_out;

  char* p = (char*)d_ws;
  float*    invT  = (float*)(p + 245760);              // 9,830,400
  float*    Rm    = (float*)(p + 10076160);            // 368,640
  float*    D2bm  = (float*)(p + 10444800);            // 1,024,000
  float*    wenvg = (float*)(p + 11468800);            // 2,293,760 (ends 13,762,560)
  float*    oa_g  = (float*)(p + 14008320);            // 5,898,240
  ushort_t* lath  = (ushort_t*)(p + 19906560);         // 2,621,440
  ushort_t* latl  = (ushort_t*)(p + 22528000);         // 2,621,440
  ushort_t* Wpack = (ushort_t*)(p + 25149440);         // 5,898,240 (ends 31,047,680)

  kAB<<<6712, 256, 0, stream>>>(Wtp, lat, Wenv, ndf, hid, evec, eidx, act,
                                w0, b0, w1, w2, Wr0, br0, Wr1, Wr2,
                                Wpack, lath, latl, oa_g, wenvg, invT, Rm, D2bm, out);
  k3_gemm<<<dim3(E_TOT/128, 9), 256, 0, stream>>>(Wpack, lath, latl, invT, oa_g);
  k4_epi<<<E_TOT/4, 256, 0, stream>>>(oa_g, Rm, D2bm, wenvg, eidx, act,
                                      Wp0, bp0, Wp1, Wp2, out);
}